// Round 3
// baseline (470.182 us; speedup 1.0000x reference)
//
#include <hip/hip_runtime.h>
#include <hip/hip_bf16.h>
#include <stdint.h>

#define NN 50000
#define NE 800000

typedef __attribute__((ext_vector_type(8))) __bf16 bf16x8;
typedef __attribute__((ext_vector_type(4))) float f32x4;

__device__ __forceinline__ float bflo(uint32_t u) { return __uint_as_float(u << 16); }
__device__ __forceinline__ float bfhi(uint32_t u) { return __uint_as_float(u & 0xffff0000u); }
__device__ __forceinline__ uint16_t f2bf(float f) {
    uint32_t u = __float_as_uint(f);
    u += 0x7fffu + ((u >> 16) & 1u);   // RNE
    return (uint16_t)(u >> 16);
}
__device__ __forceinline__ float bf2f(uint16_t h) { return __uint_as_float(((uint32_t)h) << 16); }

// ---------------- dtype detection (kept as insurance) ----------------
// flags[0]: 1 if float inputs are fp32, 0 if bf16-packed
// flags[1]: 1 if edge_index is int64, 0 if int32
__global__ __launch_bounds__(256) void detect(const uint32_t* __restrict__ xu,
                                              const int* __restrict__ ei,
                                              int* __restrict__ flags) {
    __shared__ int cnt_f, cnt_i;
    if (threadIdx.x == 0) { cnt_f = 0; cnt_i = 0; }
    __syncthreads();
    uint32_t u = xu[threadIdx.x];
    uint32_t lo = u & 0xffffu;
    uint32_t e = (lo >> 7) & 0xffu;
    int ok = (lo == 0u) || (e >= 96u && e <= 150u);
    atomicAdd(&cnt_f, ok);
    if (threadIdx.x < 64) {
        int w = ei[2 * threadIdx.x + 1];
        atomicAdd(&cnt_i, (w != 0) ? 1 : 0);
    }
    __syncthreads();
    if (threadIdx.x == 0) {
        flags[0] = (cnt_f < 192) ? 1 : 0;
        flags[1] = (cnt_i < 4) ? 1 : 0;
    }
}

// ---------------- normalization ----------------

__global__ __launch_bounds__(256) void norm_edges(const int* __restrict__ ei, const int* __restrict__ flags,
                                                  int* __restrict__ src, int* __restrict__ dst) {
    int e = blockIdx.x * 256 + threadIdx.x;
    if (e >= NE) return;
    if (flags[1]) {
        src[e] = ei[2 * e];
        dst[e] = ei[2 * NE + 2 * e];
    } else {
        src[e] = ei[e];
        dst[e] = ei[NE + e];
    }
}

// x: NN*128 floats -> packed bf16 pairs (NN*64 uint32)
__global__ __launch_bounds__(256) void norm_x(const void* __restrict__ x, const int* __restrict__ flags,
                                              uint32_t* __restrict__ out) {
    int i = blockIdx.x * 256 + threadIdx.x;  // < NN*64
    if (flags[0]) {
        float2 v = ((const float2*)x)[i];
        out[i] = (uint32_t)f2bf(v.x) | ((uint32_t)f2bf(v.y) << 16);
    } else {
        out[i] = ((const uint32_t*)x)[i];
    }
}

// all 6 weight/bias tensors -> one packed-bf16 buffer
__global__ __launch_bounds__(256) void norm_weights(const void* __restrict__ w1l, const void* __restrict__ b1,
                                                    const void* __restrict__ w1r, const void* __restrict__ w2l,
                                                    const void* __restrict__ b2, const void* __restrict__ w2r,
                                                    const int* __restrict__ flags, uint32_t* __restrict__ out) {
    constexpr int off[7] = {0, 16384, 16512, 32896, 49280, 49344, 65728};  // pair offsets
    int i = blockIdx.x * 256 + threadIdx.x;
    if (i >= 65728) return;
    int t = 0;
    while (i >= off[t + 1]) t++;
    const void* srcs[6] = {w1l, b1, w1r, w2l, b2, w2r};
    int j = i - off[t];
    uint32_t r;
    if (flags[0]) {
        float2 v = ((const float2*)srcs[t])[j];
        r = (uint32_t)f2bf(v.x) | ((uint32_t)f2bf(v.y) << 16);
    } else {
        r = ((const uint32_t*)srcs[t])[j];
    }
    out[i] = r;
}

// ---------------- CSR build ----------------

__global__ __launch_bounds__(256) void count_deg(const int* __restrict__ dst, int* __restrict__ deg) {
    int e = blockIdx.x * 256 + threadIdx.x;
    if (e < NE) atomicAdd(&deg[dst[e]], 1);
}

__global__ __launch_bounds__(1024) void scan_deg(const int* __restrict__ deg, int* __restrict__ row_start,
                                                 int* __restrict__ cursor, float* __restrict__ inv_deg) {
    __shared__ int sm[1024];
    __shared__ int carry_sm;
    int tid = threadIdx.x;
    if (tid == 0) carry_sm = 0;
    __syncthreads();
    int nchunk = (NN + 1023) / 1024;
    for (int c = 0; c < nchunk; c++) {
        int idx = c * 1024 + tid;
        int v = (idx < NN) ? deg[idx] : 0;
        sm[tid] = v;
        __syncthreads();
        for (int offs = 1; offs < 1024; offs <<= 1) {
            int t = (tid >= offs) ? sm[tid - offs] : 0;
            __syncthreads();
            sm[tid] += t;
            __syncthreads();
        }
        int incl = sm[tid];
        int excl = incl - v;
        int carry = carry_sm;
        if (idx < NN) {
            int rs = carry + excl;
            row_start[idx] = rs;
            cursor[idx] = rs;
            inv_deg[idx] = 1.0f / (float)(v > 0 ? v : 1);
        }
        __syncthreads();
        if (tid == 1023) carry_sm = carry + incl;
        __syncthreads();
    }
    if (tid == 0) row_start[NN] = carry_sm;
}

__global__ __launch_bounds__(256) void fill_csr(const int* __restrict__ src, const int* __restrict__ dst,
                                                int* __restrict__ cursor, int* __restrict__ csr) {
    int e = blockIdx.x * 256 + threadIdx.x;
    if (e < NE) {
        int pos = atomicAdd(&cursor[dst[e]], 1);
        csr[pos] = src[e];
    }
}

// ---------------- mean aggregation (gather over CSR) ----------------

__global__ __launch_bounds__(256) void agg_mean_128(const uint32_t* __restrict__ xu,
                                                    const int* __restrict__ row_start,
                                                    const int* __restrict__ csr,
                                                    const float* __restrict__ inv_deg,
                                                    uint32_t* __restrict__ outu) {
    int node = blockIdx.x * 4 + (threadIdx.x >> 6);
    int lane = threadIdx.x & 63;
    int beg = row_start[node], end = row_start[node + 1];
    float a0 = 0.f, a1 = 0.f, b0 = 0.f, b1 = 0.f;
    int j = beg;
    for (; j + 2 <= end; j += 2) {
        int s0 = csr[j], s1 = csr[j + 1];
        uint32_t u0 = xu[(size_t)s0 * 64 + lane];
        uint32_t u1 = xu[(size_t)s1 * 64 + lane];
        a0 += bflo(u0); a1 += bfhi(u0);
        b0 += bflo(u1); b1 += bfhi(u1);
    }
    if (j < end) {
        uint32_t u = xu[(size_t)csr[j] * 64 + lane];
        a0 += bflo(u); a1 += bfhi(u);
    }
    float sc = inv_deg[node];
    float r0 = (a0 + b0) * sc, r1 = (a1 + b1) * sc;
    outu[(size_t)node * 64 + lane] = (uint32_t)f2bf(r0) | ((uint32_t)f2bf(r1) << 16);
}

__global__ __launch_bounds__(256) void agg_mean_256(const uint2* __restrict__ xu,
                                                    const int* __restrict__ row_start,
                                                    const int* __restrict__ csr,
                                                    const float* __restrict__ inv_deg,
                                                    uint2* __restrict__ outu) {
    int node = blockIdx.x * 4 + (threadIdx.x >> 6);
    int lane = threadIdx.x & 63;
    int beg = row_start[node], end = row_start[node + 1];
    float a0 = 0.f, a1 = 0.f, a2 = 0.f, a3 = 0.f;
    float c0 = 0.f, c1 = 0.f, c2 = 0.f, c3 = 0.f;
    int j = beg;
    for (; j + 2 <= end; j += 2) {
        int s0 = csr[j], s1 = csr[j + 1];
        uint2 u0 = xu[(size_t)s0 * 64 + lane];
        uint2 u1 = xu[(size_t)s1 * 64 + lane];
        a0 += bflo(u0.x); a1 += bfhi(u0.x); a2 += bflo(u0.y); a3 += bfhi(u0.y);
        c0 += bflo(u1.x); c1 += bfhi(u1.x); c2 += bflo(u1.y); c3 += bfhi(u1.y);
    }
    if (j < end) {
        uint2 u = xu[(size_t)csr[j] * 64 + lane];
        a0 += bflo(u.x); a1 += bfhi(u.x); a2 += bflo(u.y); a3 += bfhi(u.y);
    }
    float sc = inv_deg[node];
    uint2 r;
    r.x = (uint32_t)f2bf((a0 + c0) * sc) | ((uint32_t)f2bf((a1 + c1) * sc) << 16);
    r.y = (uint32_t)f2bf((a2 + c2) * sc) | ((uint32_t)f2bf((a3 + c3) * sc) << 16);
    outu[(size_t)node * 64 + lane] = r;
}

// ---------------- weight swizzle into B-fragment layout ----------------
// W [K x N] row-major -> tiles (kt,nt); lane l holds B[kt*32 + (l>>4)*8 + j][nt*16 + (l&15)], j=0..7
__global__ __launch_bounds__(256) void swizzle_w(const uint16_t* __restrict__ W, uint16_t* __restrict__ Wsw,
                                                 int K, int N) {
    int t = blockIdx.x * 256 + threadIdx.x;
    int KT = K >> 5, NT = N >> 4;
    int tile = t >> 6, lane = t & 63;
    if (tile >= KT * NT) return;
    int kt = tile / NT, nt = tile - kt * NT;
    int n = lane & 15, q = lane >> 4;
    const uint16_t* s = W + (size_t)(kt * 32 + q * 8) * N + nt * 16 + n;
    uint16_t* d = Wsw + (size_t)tile * 512 + lane * 8;
#pragma unroll
    for (int j = 0; j < 8; j++) d[j] = s[(size_t)j * N];
}

// ---------------- dual-A GEMM: C = relu?(A1@W1 + A2@W2 + bias) ----------------
// OUT_F32: write fp32 (final layer, d_out is float*), else packed bf16 row-major
template <int K, int N, bool RELU, bool OUT_F32>
__global__ __launch_bounds__(256) void gemm_dual(const uint16_t* __restrict__ A1,
                                                 const uint16_t* __restrict__ A2,
                                                 const uint16_t* __restrict__ W1sw,
                                                 const uint16_t* __restrict__ W2sw,
                                                 const uint16_t* __restrict__ bias,
                                                 void* __restrict__ Cout) {
    constexpr int NT = N / 16;
    constexpr int KT = K / 32;
    int wave = threadIdx.x >> 6;
    int lane = threadIdx.x & 63;
    int row0 = blockIdx.x * 64 + wave * 16;
    int m = lane & 15, q = lane >> 4;
    int row = row0 + m;
    int arow = (row < NN) ? row : 0;

    f32x4 acc[NT];
#pragma unroll
    for (int nt = 0; nt < NT; nt++)
#pragma unroll
        for (int i = 0; i < 4; i++) acc[nt][i] = 0.f;

    const uint16_t* Aarr[2] = {A1, A2};
    const uint16_t* Warr[2] = {W1sw, W2sw};
#pragma unroll
    for (int hh = 0; hh < 2; hh++) {
        const uint16_t* A = Aarr[hh];
        const uint16_t* Wsw = Warr[hh];
#pragma unroll
        for (int kt = 0; kt < KT; kt++) {
            bf16x8 af = *(const bf16x8*)(A + (size_t)arow * K + (kt * 32 + q * 8));
            const uint16_t* wp = Wsw + (size_t)kt * (NT * 512) + lane * 8;
#pragma unroll
            for (int nt = 0; nt < NT; nt++) {
                bf16x8 bfr = *(const bf16x8*)(wp + nt * 512);
                acc[nt] = __builtin_amdgcn_mfma_f32_16x16x32_bf16(af, bfr, acc[nt], 0, 0, 0);
            }
        }
    }

    // C/D layout: col = lane&15, row_in_tile = (lane>>4)*4 + reg
#pragma unroll
    for (int nt = 0; nt < NT; nt++) {
        int col = nt * 16 + m;
        float bv = bf2f(bias[col]);
#pragma unroll
        for (int i = 0; i < 4; i++) {
            int r = row0 + q * 4 + i;
            if (r < NN) {
                float v = acc[nt][i] + bv;
                if (RELU) v = fmaxf(v, 0.f);
                if (OUT_F32) ((float*)Cout)[(size_t)r * N + col] = v;
                else ((uint16_t*)Cout)[(size_t)r * N + col] = f2bf(v);
            }
        }
    }
}

extern "C" void kernel_launch(void* const* d_in, const int* in_sizes, int n_in,
                              void* d_out, int out_size, void* d_ws, size_t ws_size,
                              hipStream_t stream) {
    const void* x_raw  = d_in[0];
    const int*  ei     = (const int*)d_in[1];
    const void* W1l    = d_in[2];
    const void* b1     = d_in[3];
    const void* W1r    = d_in[4];
    const void* W2l    = d_in[5];
    const void* b2     = d_in[6];
    const void* W2r    = d_in[7];

    uint8_t* ws = (uint8_t*)d_ws;
    size_t off = 0;
    auto alloc = [&](size_t b) -> void* {
        void* p = ws + off;
        off += (b + 255) & ~(size_t)255;
        return p;
    };
    int*      flags     = (int*)alloc(256);
    int*      deg       = (int*)alloc((size_t)NN * 4);
    float*    inv_deg   = (float*)alloc((size_t)NN * 4);
    int*      row_start = (int*)alloc((size_t)(NN + 1) * 4);
    int*      cursor    = (int*)alloc((size_t)NN * 4);
    int*      srcn      = (int*)alloc((size_t)NE * 4);
    int*      dstn      = (int*)alloc((size_t)NE * 4);
    int*      csr       = (int*)alloc((size_t)NE * 4);
    uint32_t* xb        = (uint32_t*)alloc((size_t)NN * 64 * 4);
    uint32_t* wbuf      = (uint32_t*)alloc(65728 * 4);
    uint16_t* agg       = (uint16_t*)alloc((size_t)NN * 256 * 2);
    uint16_t* h         = (uint16_t*)alloc((size_t)NN * 256 * 2);
    uint16_t* w1l_sw    = (uint16_t*)alloc(128 * 256 * 2);
    uint16_t* w1r_sw    = (uint16_t*)alloc(128 * 256 * 2);
    uint16_t* w2l_sw    = (uint16_t*)alloc(256 * 128 * 2);
    uint16_t* w2r_sw    = (uint16_t*)alloc(256 * 128 * 2);

    uint16_t* wb      = (uint16_t*)wbuf;
    uint16_t* w1l_n   = wb + 0;
    uint16_t* b1_n    = wb + 32768;
    uint16_t* w1r_n   = wb + 33024;
    uint16_t* w2l_n   = wb + 65792;
    uint16_t* b2_n    = wb + 98560;
    uint16_t* w2r_n   = wb + 98688;

    detect<<<1, 256, 0, stream>>>((const uint32_t*)x_raw, ei, flags);
    hipMemsetAsync(deg, 0, (size_t)NN * 4, stream);

    norm_edges<<<(NE + 255) / 256, 256, 0, stream>>>(ei, flags, srcn, dstn);
    norm_x<<<(NN * 64 + 255) / 256, 256, 0, stream>>>(x_raw, flags, xb);
    norm_weights<<<257, 256, 0, stream>>>(W1l, b1, W1r, W2l, b2, W2r, flags, wbuf);

    count_deg<<<(NE + 255) / 256, 256, 0, stream>>>(dstn, deg);
    scan_deg<<<1, 1024, 0, stream>>>(deg, row_start, cursor, inv_deg);
    fill_csr<<<(NE + 255) / 256, 256, 0, stream>>>(srcn, dstn, cursor, csr);

    swizzle_w<<<16, 256, 0, stream>>>(w1l_n, w1l_sw, 128, 256);
    swizzle_w<<<16, 256, 0, stream>>>(w1r_n, w1r_sw, 128, 256);
    swizzle_w<<<16, 256, 0, stream>>>(w2l_n, w2l_sw, 256, 128);
    swizzle_w<<<16, 256, 0, stream>>>(w2r_n, w2r_sw, 256, 128);

    agg_mean_128<<<NN / 4, 256, 0, stream>>>(xb, row_start, csr, inv_deg, (uint32_t*)agg);
    gemm_dual<128, 256, true, false><<<(NN + 63) / 64, 256, 0, stream>>>(agg, (const uint16_t*)xb, w1l_sw, w1r_sw, b1_n, h);
    agg_mean_256<<<NN / 4, 256, 0, stream>>>((const uint2*)h, row_start, csr, inv_deg, (uint2*)agg);
    gemm_dual<256, 128, false, true><<<(NN + 63) / 64, 256, 0, stream>>>(agg, h, w2l_sw, w2r_sw, b2_n, d_out);
}

// Round 4
// 389.759 us; speedup vs baseline: 1.2063x; 1.2063x over previous
//
#include <hip/hip_runtime.h>
#include <hip/hip_bf16.h>
#include <stdint.h>

#define NN 50000
#define NE 800000

typedef __attribute__((ext_vector_type(8))) __bf16 bf16x8;
typedef __attribute__((ext_vector_type(4))) float f32x4;

__device__ __forceinline__ float bflo(uint32_t u) { return __uint_as_float(u << 16); }
__device__ __forceinline__ float bfhi(uint32_t u) { return __uint_as_float(u & 0xffff0000u); }
__device__ __forceinline__ uint16_t f2bf(float f) {
    uint32_t u = __float_as_uint(f);
    u += 0x7fffu + ((u >> 16) & 1u);   // RNE
    return (uint16_t)(u >> 16);
}
__device__ __forceinline__ float bf2f(uint16_t h) { return __uint_as_float(((uint32_t)h) << 16); }

// ---------------- dtype detection (kept as insurance) ----------------
__global__ __launch_bounds__(256) void detect(const uint32_t* __restrict__ xu,
                                              const int* __restrict__ ei,
                                              int* __restrict__ flags) {
    __shared__ int cnt_f, cnt_i;
    if (threadIdx.x == 0) { cnt_f = 0; cnt_i = 0; }
    __syncthreads();
    uint32_t u = xu[threadIdx.x];
    uint32_t lo = u & 0xffffu;
    uint32_t e = (lo >> 7) & 0xffu;
    int ok = (lo == 0u) || (e >= 96u && e <= 150u);
    atomicAdd(&cnt_f, ok);
    if (threadIdx.x < 64) {
        int w = ei[2 * threadIdx.x + 1];
        atomicAdd(&cnt_i, (w != 0) ? 1 : 0);
    }
    __syncthreads();
    if (threadIdx.x == 0) {
        flags[0] = (cnt_f < 192) ? 1 : 0;
        flags[1] = (cnt_i < 4) ? 1 : 0;
    }
}

// ---------------- edge normalize + degree count (fused) ----------------
__global__ __launch_bounds__(256) void norm_edges_count(const int* __restrict__ ei, const int* __restrict__ flags,
                                                        int* __restrict__ src, int* __restrict__ dst,
                                                        int* __restrict__ deg) {
    int e = blockIdx.x * 256 + threadIdx.x;
    if (e >= NE) return;
    int s, d;
    if (flags[1]) {
        s = ei[2 * e];
        d = ei[2 * NE + 2 * e];
    } else {
        s = ei[e];
        d = ei[NE + e];
    }
    src[e] = s;
    dst[e] = d;
    atomicAdd(&deg[d], 1);
}

// x: NN*128 floats -> packed bf16 pairs
__global__ __launch_bounds__(256) void norm_x(const void* __restrict__ x, const int* __restrict__ flags,
                                              uint32_t* __restrict__ out) {
    int i = blockIdx.x * 256 + threadIdx.x;  // < NN*64
    if (flags[0]) {
        float2 v = ((const float2*)x)[i];
        out[i] = (uint32_t)f2bf(v.x) | ((uint32_t)f2bf(v.y) << 16);
    } else {
        out[i] = ((const uint32_t*)x)[i];
    }
}

__global__ __launch_bounds__(256) void norm_weights(const void* __restrict__ w1l, const void* __restrict__ b1,
                                                    const void* __restrict__ w1r, const void* __restrict__ w2l,
                                                    const void* __restrict__ b2, const void* __restrict__ w2r,
                                                    const int* __restrict__ flags, uint32_t* __restrict__ out) {
    constexpr int off[7] = {0, 16384, 16512, 32896, 49280, 49344, 65728};  // pair offsets
    int i = blockIdx.x * 256 + threadIdx.x;
    if (i >= 65728) return;
    int t = 0;
    while (i >= off[t + 1]) t++;
    const void* srcs[6] = {w1l, b1, w1r, w2l, b2, w2r};
    int j = i - off[t];
    uint32_t r;
    if (flags[0]) {
        float2 v = ((const float2*)srcs[t])[j];
        r = (uint32_t)f2bf(v.x) | ((uint32_t)f2bf(v.y) << 16);
    } else {
        r = ((const uint32_t*)srcs[t])[j];
    }
    out[i] = r;
}

// ---------------- CSR segment allocation (order-free, replaces scan) ----------------
// wave-level prefix sum of degrees + one atomicAdd per wave for the base offset
__global__ __launch_bounds__(256) void alloc_rows(const int* __restrict__ deg, int* __restrict__ counter,
                                                  int* __restrict__ row_start, int* __restrict__ cursor,
                                                  float* __restrict__ inv_deg) {
    int node = blockIdx.x * 256 + threadIdx.x;
    int lane = threadIdx.x & 63;
    int d = (node < NN) ? deg[node] : 0;
    int incl = d;
#pragma unroll
    for (int o = 1; o < 64; o <<= 1) {
        int t = __shfl_up(incl, o, 64);
        if (lane >= o) incl += t;
    }
    int excl = incl - d;
    int wave_total = __shfl(incl, 63, 64);
    int base = 0;
    if (lane == 63) base = atomicAdd(counter, wave_total);
    base = __shfl(base, 63, 64);
    if (node < NN) {
        int rs = base + excl;
        row_start[node] = rs;
        cursor[node] = rs;
        inv_deg[node] = 1.0f / (float)(d > 0 ? d : 1);
    }
}

__global__ __launch_bounds__(256) void fill_csr(const int* __restrict__ src, const int* __restrict__ dst,
                                                int* __restrict__ cursor, int* __restrict__ csr) {
    int e = blockIdx.x * 256 + threadIdx.x;
    if (e < NE) {
        int pos = atomicAdd(&cursor[dst[e]], 1);
        csr[pos] = src[e];
    }
}

// ---------------- mean aggregation (gather over CSR) ----------------

__global__ __launch_bounds__(256) void agg_mean_128(const uint32_t* __restrict__ xu,
                                                    const int* __restrict__ row_start,
                                                    const int* __restrict__ deg,
                                                    const int* __restrict__ csr,
                                                    const float* __restrict__ inv_deg,
                                                    uint32_t* __restrict__ outu) {
    int node = blockIdx.x * 4 + (threadIdx.x >> 6);
    int lane = threadIdx.x & 63;
    int beg = row_start[node], end = beg + deg[node];
    float a0 = 0.f, a1 = 0.f, b0 = 0.f, b1 = 0.f;
    int j = beg;
    for (; j + 2 <= end; j += 2) {
        int s0 = csr[j], s1 = csr[j + 1];
        uint32_t u0 = xu[(size_t)s0 * 64 + lane];
        uint32_t u1 = xu[(size_t)s1 * 64 + lane];
        a0 += bflo(u0); a1 += bfhi(u0);
        b0 += bflo(u1); b1 += bfhi(u1);
    }
    if (j < end) {
        uint32_t u = xu[(size_t)csr[j] * 64 + lane];
        a0 += bflo(u); a1 += bfhi(u);
    }
    float sc = inv_deg[node];
    float r0 = (a0 + b0) * sc, r1 = (a1 + b1) * sc;
    outu[(size_t)node * 64 + lane] = (uint32_t)f2bf(r0) | ((uint32_t)f2bf(r1) << 16);
}

__global__ __launch_bounds__(256) void agg_mean_256(const uint2* __restrict__ xu,
                                                    const int* __restrict__ row_start,
                                                    const int* __restrict__ deg,
                                                    const int* __restrict__ csr,
                                                    const float* __restrict__ inv_deg,
                                                    uint2* __restrict__ outu) {
    int node = blockIdx.x * 4 + (threadIdx.x >> 6);
    int lane = threadIdx.x & 63;
    int beg = row_start[node], end = beg + deg[node];
    float a0 = 0.f, a1 = 0.f, a2 = 0.f, a3 = 0.f;
    float c0 = 0.f, c1 = 0.f, c2 = 0.f, c3 = 0.f;
    int j = beg;
    for (; j + 2 <= end; j += 2) {
        int s0 = csr[j], s1 = csr[j + 1];
        uint2 u0 = xu[(size_t)s0 * 64 + lane];
        uint2 u1 = xu[(size_t)s1 * 64 + lane];
        a0 += bflo(u0.x); a1 += bfhi(u0.x); a2 += bflo(u0.y); a3 += bfhi(u0.y);
        c0 += bflo(u1.x); c1 += bfhi(u1.x); c2 += bflo(u1.y); c3 += bfhi(u1.y);
    }
    if (j < end) {
        uint2 u = xu[(size_t)csr[j] * 64 + lane];
        a0 += bflo(u.x); a1 += bfhi(u.x); a2 += bflo(u.y); a3 += bfhi(u.y);
    }
    float sc = inv_deg[node];
    uint2 r;
    r.x = (uint32_t)f2bf((a0 + c0) * sc) | ((uint32_t)f2bf((a1 + c1) * sc) << 16);
    r.y = (uint32_t)f2bf((a2 + c2) * sc) | ((uint32_t)f2bf((a3 + c3) * sc) << 16);
    outu[(size_t)node * 64 + lane] = r;
}

// ---------------- weight swizzle into B-fragment layout ----------------
__global__ __launch_bounds__(256) void swizzle_w(const uint16_t* __restrict__ W, uint16_t* __restrict__ Wsw,
                                                 int K, int N) {
    int t = blockIdx.x * 256 + threadIdx.x;
    int KT = K >> 5, NT = N >> 4;
    int tile = t >> 6, lane = t & 63;
    if (tile >= KT * NT) return;
    int kt = tile / NT, nt = tile - kt * NT;
    int n = lane & 15, q = lane >> 4;
    const uint16_t* s = W + (size_t)(kt * 32 + q * 8) * N + nt * 16 + n;
    uint16_t* d = Wsw + (size_t)tile * 512 + lane * 8;
#pragma unroll
    for (int j = 0; j < 8; j++) d[j] = s[(size_t)j * N];
}

// ---------------- dual-A GEMM: C = relu?(A1@W1 + A2@W2 + bias) ----------------
template <int K, int N, bool RELU, bool OUT_F32>
__global__ __launch_bounds__(256) void gemm_dual(const uint16_t* __restrict__ A1,
                                                 const uint16_t* __restrict__ A2,
                                                 const uint16_t* __restrict__ W1sw,
                                                 const uint16_t* __restrict__ W2sw,
                                                 const uint16_t* __restrict__ bias,
                                                 void* __restrict__ Cout) {
    constexpr int NT = N / 16;
    constexpr int KT = K / 32;
    int wave = threadIdx.x >> 6;
    int lane = threadIdx.x & 63;
    int row0 = blockIdx.x * 64 + wave * 16;
    int m = lane & 15, q = lane >> 4;
    int row = row0 + m;
    int arow = (row < NN) ? row : 0;

    f32x4 acc[NT];
#pragma unroll
    for (int nt = 0; nt < NT; nt++)
#pragma unroll
        for (int i = 0; i < 4; i++) acc[nt][i] = 0.f;

    const uint16_t* Aarr[2] = {A1, A2};
    const uint16_t* Warr[2] = {W1sw, W2sw};
#pragma unroll
    for (int hh = 0; hh < 2; hh++) {
        const uint16_t* A = Aarr[hh];
        const uint16_t* Wsw = Warr[hh];
#pragma unroll
        for (int kt = 0; kt < KT; kt++) {
            bf16x8 af = *(const bf16x8*)(A + (size_t)arow * K + (kt * 32 + q * 8));
            const uint16_t* wp = Wsw + (size_t)kt * (NT * 512) + lane * 8;
#pragma unroll
            for (int nt = 0; nt < NT; nt++) {
                bf16x8 bfr = *(const bf16x8*)(wp + nt * 512);
                acc[nt] = __builtin_amdgcn_mfma_f32_16x16x32_bf16(af, bfr, acc[nt], 0, 0, 0);
            }
        }
    }

#pragma unroll
    for (int nt = 0; nt < NT; nt++) {
        int col = nt * 16 + m;
        float bv = bf2f(bias[col]);
#pragma unroll
        for (int i = 0; i < 4; i++) {
            int r = row0 + q * 4 + i;
            if (r < NN) {
                float v = acc[nt][i] + bv;
                if (RELU) v = fmaxf(v, 0.f);
                if (OUT_F32) ((float*)Cout)[(size_t)r * N + col] = v;
                else ((uint16_t*)Cout)[(size_t)r * N + col] = f2bf(v);
            }
        }
    }
}

extern "C" void kernel_launch(void* const* d_in, const int* in_sizes, int n_in,
                              void* d_out, int out_size, void* d_ws, size_t ws_size,
                              hipStream_t stream) {
    const void* x_raw  = d_in[0];
    const int*  ei     = (const int*)d_in[1];
    const void* W1l    = d_in[2];
    const void* b1     = d_in[3];
    const void* W1r    = d_in[4];
    const void* W2l    = d_in[5];
    const void* b2     = d_in[6];
    const void* W2r    = d_in[7];

    uint8_t* ws = (uint8_t*)d_ws;
    size_t off = 0;
    auto alloc = [&](size_t b) -> void* {
        void* p = ws + off;
        off += (b + 255) & ~(size_t)255;
        return p;
    };
    int*      flags     = (int*)alloc(256);
    int*      counter   = (int*)alloc(256);
    int*      deg       = (int*)alloc((size_t)NN * 4);
    float*    inv_deg   = (float*)alloc((size_t)NN * 4);
    int*      row_start = (int*)alloc((size_t)NN * 4);
    int*      cursor    = (int*)alloc((size_t)NN * 4);
    int*      srcn      = (int*)alloc((size_t)NE * 4);
    int*      dstn      = (int*)alloc((size_t)NE * 4);
    int*      csr       = (int*)alloc((size_t)NE * 4);
    uint32_t* xb        = (uint32_t*)alloc((size_t)NN * 64 * 4);
    uint32_t* wbuf      = (uint32_t*)alloc(65728 * 4);
    uint16_t* agg       = (uint16_t*)alloc((size_t)NN * 256 * 2);
    uint16_t* h         = (uint16_t*)alloc((size_t)NN * 256 * 2);
    uint16_t* w1l_sw    = (uint16_t*)alloc(128 * 256 * 2);
    uint16_t* w1r_sw    = (uint16_t*)alloc(128 * 256 * 2);
    uint16_t* w2l_sw    = (uint16_t*)alloc(256 * 128 * 2);
    uint16_t* w2r_sw    = (uint16_t*)alloc(256 * 128 * 2);

    uint16_t* wb      = (uint16_t*)wbuf;
    uint16_t* w1l_n   = wb + 0;
    uint16_t* b1_n    = wb + 32768;
    uint16_t* w1r_n   = wb + 33024;
    uint16_t* w2l_n   = wb + 65792;
    uint16_t* b2_n    = wb + 98560;
    uint16_t* w2r_n   = wb + 98688;

    detect<<<1, 256, 0, stream>>>((const uint32_t*)x_raw, ei, flags);
    hipMemsetAsync(counter, 0, 256, stream);
    hipMemsetAsync(deg, 0, (size_t)NN * 4, stream);

    norm_edges_count<<<(NE + 255) / 256, 256, 0, stream>>>(ei, flags, srcn, dstn, deg);
    norm_x<<<(NN * 64 + 255) / 256, 256, 0, stream>>>(x_raw, flags, xb);
    norm_weights<<<257, 256, 0, stream>>>(W1l, b1, W1r, W2l, b2, W2r, flags, wbuf);

    alloc_rows<<<(NN + 255) / 256, 256, 0, stream>>>(deg, counter, row_start, cursor, inv_deg);
    fill_csr<<<(NE + 255) / 256, 256, 0, stream>>>(srcn, dstn, cursor, csr);

    swizzle_w<<<16, 256, 0, stream>>>(w1l_n, w1l_sw, 128, 256);
    swizzle_w<<<16, 256, 0, stream>>>(w1r_n, w1r_sw, 128, 256);
    swizzle_w<<<16, 256, 0, stream>>>(w2l_n, w2l_sw, 256, 128);
    swizzle_w<<<16, 256, 0, stream>>>(w2r_n, w2r_sw, 256, 128);

    agg_mean_128<<<NN / 4, 256, 0, stream>>>(xb, row_start, deg, csr, inv_deg, (uint32_t*)agg);
    gemm_dual<128, 256, true, false><<<(NN + 63) / 64, 256, 0, stream>>>(agg, (const uint16_t*)xb, w1l_sw, w1r_sw, b1_n, h);
    agg_mean_256<<<NN / 4, 256, 0, stream>>>((const uint2*)h, row_start, deg, csr, inv_deg, (uint2*)agg);
    gemm_dual<256, 128, false, true><<<(NN + 63) / 64, 256, 0, stream>>>(agg, h, w2l_sw, w2r_sw, b2_n, d_out);
}

// Round 5
// 362.639 us; speedup vs baseline: 1.2966x; 1.0748x over previous
//
#include <hip/hip_runtime.h>
#include <hip/hip_bf16.h>
#include <stdint.h>

#define NN 50000
#define NE 800000

typedef __attribute__((ext_vector_type(8))) __bf16 bf16x8;
typedef __attribute__((ext_vector_type(4))) float f32x4;

__device__ __forceinline__ float bflo(uint32_t u) { return __uint_as_float(u << 16); }
__device__ __forceinline__ float bfhi(uint32_t u) { return __uint_as_float(u & 0xffff0000u); }
__device__ __forceinline__ uint16_t f2bf(float f) {
    uint32_t u = __float_as_uint(f);
    u += 0x7fffu + ((u >> 16) & 1u);   // RNE
    return (uint16_t)(u >> 16);
}
__device__ __forceinline__ float bf2f(uint16_t h) { return __uint_as_float(((uint32_t)h) << 16); }

// ---------------- dtype detection (insurance) ----------------
__global__ __launch_bounds__(256) void detect(const uint32_t* __restrict__ xu,
                                              const int* __restrict__ ei,
                                              int* __restrict__ flags) {
    __shared__ int cnt_f, cnt_i;
    if (threadIdx.x == 0) { cnt_f = 0; cnt_i = 0; }
    __syncthreads();
    uint32_t u = xu[threadIdx.x];
    uint32_t lo = u & 0xffffu;
    uint32_t e = (lo >> 7) & 0xffu;
    int ok = (lo == 0u) || (e >= 96u && e <= 150u);
    atomicAdd(&cnt_f, ok);
    if (threadIdx.x < 64) {
        int w = ei[2 * threadIdx.x + 1];
        atomicAdd(&cnt_i, (w != 0) ? 1 : 0);
    }
    __syncthreads();
    if (threadIdx.x == 0) {
        flags[0] = (cnt_f < 192) ? 1 : 0;
        flags[1] = (cnt_i < 4) ? 1 : 0;
    }
}

// ---------------- edge normalize + degree count (fused) ----------------
__global__ __launch_bounds__(256) void norm_edges_count(const int* __restrict__ ei, const int* __restrict__ flags,
                                                        int* __restrict__ src, int* __restrict__ dst,
                                                        int* __restrict__ deg) {
    int e = blockIdx.x * 256 + threadIdx.x;
    if (e >= NE) return;
    int s, d;
    if (flags[1]) {
        s = ei[2 * e];
        d = ei[2 * NE + 2 * e];
    } else {
        s = ei[e];
        d = ei[NE + e];
    }
    src[e] = s;
    dst[e] = d;
    atomicAdd(&deg[d], 1);
}

__global__ __launch_bounds__(256) void norm_x(const void* __restrict__ x, const int* __restrict__ flags,
                                              uint32_t* __restrict__ out) {
    int i = blockIdx.x * 256 + threadIdx.x;  // < NN*64
    if (flags[0]) {
        float2 v = ((const float2*)x)[i];
        out[i] = (uint32_t)f2bf(v.x) | ((uint32_t)f2bf(v.y) << 16);
    } else {
        out[i] = ((const uint32_t*)x)[i];
    }
}

__global__ __launch_bounds__(256) void norm_weights(const void* __restrict__ w1l, const void* __restrict__ b1,
                                                    const void* __restrict__ w1r, const void* __restrict__ w2l,
                                                    const void* __restrict__ b2, const void* __restrict__ w2r,
                                                    const int* __restrict__ flags, uint32_t* __restrict__ out) {
    constexpr int off[7] = {0, 16384, 16512, 32896, 49280, 49344, 65728};  // pair offsets
    int i = blockIdx.x * 256 + threadIdx.x;
    if (i >= 65728) return;
    int t = 0;
    while (i >= off[t + 1]) t++;
    const void* srcs[6] = {w1l, b1, w1r, w2l, b2, w2r};
    int j = i - off[t];
    uint32_t r;
    if (flags[0]) {
        float2 v = ((const float2*)srcs[t])[j];
        r = (uint32_t)f2bf(v.x) | ((uint32_t)f2bf(v.y) << 16);
    } else {
        r = ((const uint32_t*)srcs[t])[j];
    }
    out[i] = r;
}

// ---------------- CSR segment allocation (order-free) ----------------
__global__ __launch_bounds__(256) void alloc_rows(const int* __restrict__ deg, int* __restrict__ counter,
                                                  int* __restrict__ row_start, int* __restrict__ cursor,
                                                  float* __restrict__ inv_deg) {
    int node = blockIdx.x * 256 + threadIdx.x;
    int lane = threadIdx.x & 63;
    int d = (node < NN) ? deg[node] : 0;
    int incl = d;
#pragma unroll
    for (int o = 1; o < 64; o <<= 1) {
        int t = __shfl_up(incl, o, 64);
        if (lane >= o) incl += t;
    }
    int excl = incl - d;
    int wave_total = __shfl(incl, 63, 64);
    int base = 0;
    if (lane == 63) base = atomicAdd(counter, wave_total);
    base = __shfl(base, 63, 64);
    if (node < NN) {
        int rs = base + excl;
        row_start[node] = rs;
        cursor[node] = rs;
        inv_deg[node] = 1.0f / (float)(d > 0 ? d : 1);
    }
}

__global__ __launch_bounds__(256) void fill_csr(const int* __restrict__ src, const int* __restrict__ dst,
                                                int* __restrict__ cursor, int* __restrict__ csr) {
    int e = blockIdx.x * 256 + threadIdx.x;
    if (e < NE) {
        int pos = atomicAdd(&cursor[dst[e]], 1);
        csr[pos] = src[e];
    }
}

// ---------------- mean aggregation over 128-wide packed bf16 ----------------
// wave per node, lane holds elements {2*lane, 2*lane+1}; unroll x4
__global__ __launch_bounds__(256) void agg_mean_128(const uint32_t* __restrict__ xu,
                                                    const int* __restrict__ row_start,
                                                    const int* __restrict__ deg,
                                                    const int* __restrict__ csr,
                                                    const float* __restrict__ inv_deg,
                                                    uint32_t* __restrict__ outu) {
    int node = blockIdx.x * 4 + (threadIdx.x >> 6);
    int lane = threadIdx.x & 63;
    int beg = row_start[node], end = beg + deg[node];
    float a0 = 0.f, a1 = 0.f, b0 = 0.f, b1 = 0.f;
    float c0 = 0.f, c1 = 0.f, d0 = 0.f, d1 = 0.f;
    int j = beg;
    for (; j + 4 <= end; j += 4) {
        int s0 = csr[j], s1 = csr[j + 1], s2 = csr[j + 2], s3 = csr[j + 3];
        uint32_t u0 = xu[(size_t)s0 * 64 + lane];
        uint32_t u1 = xu[(size_t)s1 * 64 + lane];
        uint32_t u2 = xu[(size_t)s2 * 64 + lane];
        uint32_t u3 = xu[(size_t)s3 * 64 + lane];
        a0 += bflo(u0); a1 += bfhi(u0);
        b0 += bflo(u1); b1 += bfhi(u1);
        c0 += bflo(u2); c1 += bfhi(u2);
        d0 += bflo(u3); d1 += bfhi(u3);
    }
    for (; j < end; j++) {
        uint32_t u = xu[(size_t)csr[j] * 64 + lane];
        a0 += bflo(u); a1 += bfhi(u);
    }
    float sc = inv_deg[node];
    float r0 = ((a0 + b0) + (c0 + d0)) * sc, r1 = ((a1 + b1) + (c1 + d1)) * sc;
    outu[(size_t)node * 64 + lane] = (uint32_t)f2bf(r0) | ((uint32_t)f2bf(r1) << 16);
}

// final: out = mean_gather(t) + u, fp32 out (layer-2 right term precomputed in u)
__global__ __launch_bounds__(256) void agg_final_128(const uint32_t* __restrict__ tu,
                                                     const int* __restrict__ row_start,
                                                     const int* __restrict__ deg,
                                                     const int* __restrict__ csr,
                                                     const float* __restrict__ inv_deg,
                                                     const float2* __restrict__ u,
                                                     float2* __restrict__ out) {
    int node = blockIdx.x * 4 + (threadIdx.x >> 6);
    int lane = threadIdx.x & 63;
    int beg = row_start[node], end = beg + deg[node];
    float a0 = 0.f, a1 = 0.f, b0 = 0.f, b1 = 0.f;
    float c0 = 0.f, c1 = 0.f, d0 = 0.f, d1 = 0.f;
    int j = beg;
    for (; j + 4 <= end; j += 4) {
        int s0 = csr[j], s1 = csr[j + 1], s2 = csr[j + 2], s3 = csr[j + 3];
        uint32_t u0 = tu[(size_t)s0 * 64 + lane];
        uint32_t u1 = tu[(size_t)s1 * 64 + lane];
        uint32_t u2 = tu[(size_t)s2 * 64 + lane];
        uint32_t u3 = tu[(size_t)s3 * 64 + lane];
        a0 += bflo(u0); a1 += bfhi(u0);
        b0 += bflo(u1); b1 += bfhi(u1);
        c0 += bflo(u2); c1 += bfhi(u2);
        d0 += bflo(u3); d1 += bfhi(u3);
    }
    for (; j < end; j++) {
        uint32_t uu = tu[(size_t)csr[j] * 64 + lane];
        a0 += bflo(uu); a1 += bfhi(uu);
    }
    float sc = inv_deg[node];
    float2 uv = u[(size_t)node * 64 + lane];
    float2 r;
    r.x = ((a0 + b0) + (c0 + d0)) * sc + uv.x;
    r.y = ((a1 + b1) + (c1 + d1)) * sc + uv.y;
    out[(size_t)node * 64 + lane] = r;
}

// ---------------- weight swizzle into B-fragment layout ----------------
__global__ __launch_bounds__(256) void swizzle_w(const uint16_t* __restrict__ W, uint16_t* __restrict__ Wsw,
                                                 int K, int N) {
    int t = blockIdx.x * 256 + threadIdx.x;
    int KT = K >> 5, NT = N >> 4;
    int tile = t >> 6, lane = t & 63;
    if (tile >= KT * NT) return;
    int kt = tile / NT, nt = tile - kt * NT;
    int n = lane & 15, q = lane >> 4;
    const uint16_t* s = W + (size_t)(kt * 32 + q * 8) * N + nt * 16 + n;
    uint16_t* d = Wsw + (size_t)tile * 512 + lane * 8;
#pragma unroll
    for (int j = 0; j < 8; j++) d[j] = s[(size_t)j * N];
}

// ---------------- layer-1 GEMM: h = relu(A1@W1 + A2@W2 + bias), bf16 out ----------------
template <int K, int N>
__global__ __launch_bounds__(256) void gemm_dualA(const uint16_t* __restrict__ A1,
                                                  const uint16_t* __restrict__ A2,
                                                  const uint16_t* __restrict__ W1sw,
                                                  const uint16_t* __restrict__ W2sw,
                                                  const uint16_t* __restrict__ bias,
                                                  uint16_t* __restrict__ C) {
    constexpr int NT = N / 16;
    constexpr int KT = K / 32;
    int wave = threadIdx.x >> 6;
    int lane = threadIdx.x & 63;
    int row0 = blockIdx.x * 64 + wave * 16;
    int m = lane & 15, q = lane >> 4;
    int row = row0 + m;
    int arow = (row < NN) ? row : 0;

    f32x4 acc[NT];
#pragma unroll
    for (int nt = 0; nt < NT; nt++)
#pragma unroll
        for (int i = 0; i < 4; i++) acc[nt][i] = 0.f;

    const uint16_t* Aarr[2] = {A1, A2};
    const uint16_t* Warr[2] = {W1sw, W2sw};
#pragma unroll
    for (int hh = 0; hh < 2; hh++) {
        const uint16_t* A = Aarr[hh];
        const uint16_t* Wsw = Warr[hh];
#pragma unroll
        for (int kt = 0; kt < KT; kt++) {
            bf16x8 af = *(const bf16x8*)(A + (size_t)arow * K + (kt * 32 + q * 8));
            const uint16_t* wp = Wsw + (size_t)kt * (NT * 512) + lane * 8;
#pragma unroll
            for (int nt = 0; nt < NT; nt++) {
                bf16x8 bfr = *(const bf16x8*)(wp + nt * 512);
                acc[nt] = __builtin_amdgcn_mfma_f32_16x16x32_bf16(af, bfr, acc[nt], 0, 0, 0);
            }
        }
    }

#pragma unroll
    for (int nt = 0; nt < NT; nt++) {
        int col = nt * 16 + m;
        float bv = bf2f(bias[col]);
#pragma unroll
        for (int i = 0; i < 4; i++) {
            int r = row0 + q * 4 + i;
            if (r < NN) {
                float v = fmaxf(acc[nt][i] + bv, 0.f);
                C[(size_t)r * N + col] = f2bf(v);
            }
        }
    }
}

// ---------------- layer-2 GEMM (dual-B): t = A@W1 (bf16), u = A@W2 + bias (fp32) ----------------
template <int K, int N>
__global__ __launch_bounds__(256) void gemm_dualB(const uint16_t* __restrict__ A,
                                                  const uint16_t* __restrict__ W1sw,
                                                  const uint16_t* __restrict__ W2sw,
                                                  const uint16_t* __restrict__ bias,
                                                  uint16_t* __restrict__ T,
                                                  float* __restrict__ U) {
    constexpr int NT = N / 16;
    constexpr int KT = K / 32;
    int wave = threadIdx.x >> 6;
    int lane = threadIdx.x & 63;
    int row0 = blockIdx.x * 64 + wave * 16;
    int m = lane & 15, q = lane >> 4;
    int row = row0 + m;
    int arow = (row < NN) ? row : 0;

    f32x4 acc1[NT], acc2[NT];
#pragma unroll
    for (int nt = 0; nt < NT; nt++)
#pragma unroll
        for (int i = 0; i < 4; i++) { acc1[nt][i] = 0.f; acc2[nt][i] = 0.f; }

#pragma unroll
    for (int kt = 0; kt < KT; kt++) {
        bf16x8 af = *(const bf16x8*)(A + (size_t)arow * K + (kt * 32 + q * 8));
        const uint16_t* wp1 = W1sw + (size_t)kt * (NT * 512) + lane * 8;
        const uint16_t* wp2 = W2sw + (size_t)kt * (NT * 512) + lane * 8;
#pragma unroll
        for (int nt = 0; nt < NT; nt++) {
            bf16x8 b1 = *(const bf16x8*)(wp1 + nt * 512);
            bf16x8 b2 = *(const bf16x8*)(wp2 + nt * 512);
            acc1[nt] = __builtin_amdgcn_mfma_f32_16x16x32_bf16(af, b1, acc1[nt], 0, 0, 0);
            acc2[nt] = __builtin_amdgcn_mfma_f32_16x16x32_bf16(af, b2, acc2[nt], 0, 0, 0);
        }
    }

#pragma unroll
    for (int nt = 0; nt < NT; nt++) {
        int col = nt * 16 + m;
        float bv = bf2f(bias[col]);
#pragma unroll
        for (int i = 0; i < 4; i++) {
            int r = row0 + q * 4 + i;
            if (r < NN) {
                T[(size_t)r * N + col] = f2bf(acc1[nt][i]);
                U[(size_t)r * N + col] = acc2[nt][i] + bv;
            }
        }
    }
}

extern "C" void kernel_launch(void* const* d_in, const int* in_sizes, int n_in,
                              void* d_out, int out_size, void* d_ws, size_t ws_size,
                              hipStream_t stream) {
    const void* x_raw  = d_in[0];
    const int*  ei     = (const int*)d_in[1];
    const void* W1l    = d_in[2];
    const void* b1     = d_in[3];
    const void* W1r    = d_in[4];
    const void* W2l    = d_in[5];
    const void* b2     = d_in[6];
    const void* W2r    = d_in[7];

    uint8_t* ws = (uint8_t*)d_ws;
    size_t off = 0;
    auto alloc = [&](size_t b) -> void* {
        void* p = ws + off;
        off += (b + 255) & ~(size_t)255;
        return p;
    };
    int*      flags     = (int*)alloc(256);
    int*      counter   = (int*)alloc(256);
    int*      deg       = (int*)alloc((size_t)NN * 4);
    float*    inv_deg   = (float*)alloc((size_t)NN * 4);
    int*      row_start = (int*)alloc((size_t)NN * 4);
    int*      cursor    = (int*)alloc((size_t)NN * 4);
    int*      srcn      = (int*)alloc((size_t)NE * 4);
    int*      dstn      = (int*)alloc((size_t)NE * 4);
    int*      csr       = (int*)alloc((size_t)NE * 4);
    uint32_t* xb        = (uint32_t*)alloc((size_t)NN * 64 * 4);
    uint32_t* wbuf      = (uint32_t*)alloc(65728 * 4);
    uint16_t* agg       = (uint16_t*)alloc((size_t)NN * 128 * 2);
    uint16_t* h         = (uint16_t*)alloc((size_t)NN * 256 * 2);
    uint16_t* t         = (uint16_t*)alloc((size_t)NN * 128 * 2);
    float*    u         = (float*)alloc((size_t)NN * 128 * 4);
    uint16_t* w1l_sw    = (uint16_t*)alloc(128 * 256 * 2);
    uint16_t* w1r_sw    = (uint16_t*)alloc(128 * 256 * 2);
    uint16_t* w2l_sw    = (uint16_t*)alloc(256 * 128 * 2);
    uint16_t* w2r_sw    = (uint16_t*)alloc(256 * 128 * 2);

    uint16_t* wb      = (uint16_t*)wbuf;
    uint16_t* w1l_n   = wb + 0;
    uint16_t* b1_n    = wb + 32768;
    uint16_t* w1r_n   = wb + 33024;
    uint16_t* w2l_n   = wb + 65792;
    uint16_t* b2_n    = wb + 98560;
    uint16_t* w2r_n   = wb + 98688;

    detect<<<1, 256, 0, stream>>>((const uint32_t*)x_raw, ei, flags);
    hipMemsetAsync(counter, 0, 256, stream);
    hipMemsetAsync(deg, 0, (size_t)NN * 4, stream);

    norm_edges_count<<<(NE + 255) / 256, 256, 0, stream>>>(ei, flags, srcn, dstn, deg);
    norm_x<<<(NN * 64 + 255) / 256, 256, 0, stream>>>(x_raw, flags, xb);
    norm_weights<<<257, 256, 0, stream>>>(W1l, b1, W1r, W2l, b2, W2r, flags, wbuf);

    alloc_rows<<<(NN + 255) / 256, 256, 0, stream>>>(deg, counter, row_start, cursor, inv_deg);
    fill_csr<<<(NE + 255) / 256, 256, 0, stream>>>(srcn, dstn, cursor, csr);

    swizzle_w<<<16, 256, 0, stream>>>(w1l_n, w1l_sw, 128, 256);
    swizzle_w<<<16, 256, 0, stream>>>(w1r_n, w1r_sw, 128, 256);
    swizzle_w<<<16, 256, 0, stream>>>(w2l_n, w2l_sw, 256, 128);
    swizzle_w<<<16, 256, 0, stream>>>(w2r_n, w2r_sw, 256, 128);

    // layer 1: agg = A·x ; h = relu(agg@W1l + x@W1r + b1)
    agg_mean_128<<<NN / 4, 256, 0, stream>>>(xb, row_start, deg, csr, inv_deg, (uint32_t*)agg);
    gemm_dualA<128, 256><<<(NN + 63) / 64, 256, 0, stream>>>(agg, (const uint16_t*)xb, w1l_sw, w1r_sw, b1_n, h);
    // layer 2 (refactored): t = h@W2l, u = h@W2r + b2 ; out = A·t + u
    gemm_dualB<256, 128><<<(NN + 63) / 64, 256, 0, stream>>>(h, w2l_sw, w2r_sw, b2_n, t, u);
    agg_final_128<<<NN / 4, 256, 0, stream>>>((const uint32_t*)t, row_start, deg, csr, inv_deg,
                                              (const float2*)u, (float2*)d_out);
}

// Round 7
// 350.166 us; speedup vs baseline: 1.3427x; 1.0356x over previous
//
#include <hip/hip_runtime.h>
#include <hip/hip_bf16.h>
#include <stdint.h>

#define NN 50000
#define NE 800000

typedef __attribute__((ext_vector_type(8))) __bf16 bf16x8;
typedef __attribute__((ext_vector_type(4))) float f32x4;

__device__ __forceinline__ float bflo(uint32_t u) { return __uint_as_float(u << 16); }
__device__ __forceinline__ float bfhi(uint32_t u) { return __uint_as_float(u & 0xffff0000u); }
__device__ __forceinline__ uint16_t f2bf(float f) {
    uint32_t u = __float_as_uint(f);
    u += 0x7fffu + ((u >> 16) & 1u);   // RNE
    return (uint16_t)(u >> 16);
}
__device__ __forceinline__ float bf2f(uint16_t h) { return __uint_as_float(((uint32_t)h) << 16); }

// ---------------- dtype detection (insurance) ----------------
__global__ __launch_bounds__(256) void detect(const uint32_t* __restrict__ xu,
                                              const int* __restrict__ ei,
                                              int* __restrict__ flags) {
    __shared__ int cnt_f, cnt_i;
    if (threadIdx.x == 0) { cnt_f = 0; cnt_i = 0; }
    __syncthreads();
    uint32_t u = xu[threadIdx.x];
    uint32_t lo = u & 0xffffu;
    uint32_t e = (lo >> 7) & 0xffu;
    int ok = (lo == 0u) || (e >= 96u && e <= 150u);
    atomicAdd(&cnt_f, ok);
    if (threadIdx.x < 64) {
        int w = ei[2 * threadIdx.x + 1];
        atomicAdd(&cnt_i, (w != 0) ? 1 : 0);
    }
    __syncthreads();
    if (threadIdx.x == 0) {
        flags[0] = (cnt_f < 192) ? 1 : 0;
        flags[1] = (cnt_i < 4) ? 1 : 0;
    }
}

// ---------------- edge normalize + degree count (fused) ----------------
__global__ __launch_bounds__(256) void norm_edges_count(const int* __restrict__ ei, const int* __restrict__ flags,
                                                        int* __restrict__ src, int* __restrict__ dst,
                                                        int* __restrict__ deg) {
    int e = blockIdx.x * 256 + threadIdx.x;
    if (e >= NE) return;
    int s, d;
    if (flags[1]) {
        s = ei[2 * e];
        d = ei[2 * NE + 2 * e];
    } else {
        s = ei[e];
        d = ei[NE + e];
    }
    src[e] = s;
    dst[e] = d;
    atomicAdd(&deg[d], 1);
}

__global__ __launch_bounds__(256) void norm_x(const void* __restrict__ x, const int* __restrict__ flags,
                                              uint32_t* __restrict__ out) {
    int i = blockIdx.x * 256 + threadIdx.x;  // < NN*64
    if (flags[0]) {
        float2 v = ((const float2*)x)[i];
        out[i] = (uint32_t)f2bf(v.x) | ((uint32_t)f2bf(v.y) << 16);
    } else {
        out[i] = ((const uint32_t*)x)[i];
    }
}

__global__ __launch_bounds__(256) void norm_weights(const void* __restrict__ w1l, const void* __restrict__ b1,
                                                    const void* __restrict__ w1r, const void* __restrict__ w2l,
                                                    const void* __restrict__ b2, const void* __restrict__ w2r,
                                                    const int* __restrict__ flags, uint32_t* __restrict__ out) {
    constexpr int off[7] = {0, 16384, 16512, 32896, 49280, 49344, 65728};  // pair offsets
    int i = blockIdx.x * 256 + threadIdx.x;
    if (i >= 65728) return;
    int t = 0;
    while (i >= off[t + 1]) t++;
    const void* srcs[6] = {w1l, b1, w1r, w2l, b2, w2r};
    int j = i - off[t];
    uint32_t r;
    if (flags[0]) {
        float2 v = ((const float2*)srcs[t])[j];
        r = (uint32_t)f2bf(v.x) | ((uint32_t)f2bf(v.y) << 16);
    } else {
        r = ((const uint32_t*)srcs[t])[j];
    }
    out[i] = r;
}

// ---------------- CSR segment allocation (order-free) ----------------
__global__ __launch_bounds__(256) void alloc_rows(const int* __restrict__ deg, int* __restrict__ counter,
                                                  int* __restrict__ row_start, int* __restrict__ cursor,
                                                  float* __restrict__ inv_deg) {
    int node = blockIdx.x * 256 + threadIdx.x;
    int lane = threadIdx.x & 63;
    int d = (node < NN) ? deg[node] : 0;
    int incl = d;
#pragma unroll
    for (int o = 1; o < 64; o <<= 1) {
        int t = __shfl_up(incl, o, 64);
        if (lane >= o) incl += t;
    }
    int excl = incl - d;
    int wave_total = __shfl(incl, 63, 64);
    int base = 0;
    if (lane == 63) base = atomicAdd(counter, wave_total);
    base = __shfl(base, 63, 64);
    if (node < NN) {
        int rs = base + excl;
        row_start[node] = rs;
        cursor[node] = rs;
        inv_deg[node] = 1.0f / (float)(d > 0 ? d : 1);
    }
}

__global__ __launch_bounds__(256) void fill_csr(const int* __restrict__ src, const int* __restrict__ dst,
                                                int* __restrict__ cursor, int* __restrict__ csr) {
    int e = blockIdx.x * 256 + threadIdx.x;
    if (e < NE) {
        int pos = atomicAdd(&cursor[dst[e]], 1);
        csr[pos] = src[e];
    }
}

// ---------------- mean aggregation over 128-wide packed bf16 ----------------
__global__ __launch_bounds__(256) void agg_mean_128(const uint32_t* __restrict__ xu,
                                                    const int* __restrict__ row_start,
                                                    const int* __restrict__ deg,
                                                    const int* __restrict__ csr,
                                                    const float* __restrict__ inv_deg,
                                                    uint32_t* __restrict__ outu) {
    int node = blockIdx.x * 4 + (threadIdx.x >> 6);
    int lane = threadIdx.x & 63;
    int beg = row_start[node], end = beg + deg[node];
    float a0 = 0.f, a1 = 0.f, b0 = 0.f, b1 = 0.f;
    float c0 = 0.f, c1 = 0.f, d0 = 0.f, d1 = 0.f;
    int j = beg;
    for (; j + 4 <= end; j += 4) {
        int s0 = csr[j], s1 = csr[j + 1], s2 = csr[j + 2], s3 = csr[j + 3];
        uint32_t u0 = xu[(size_t)s0 * 64 + lane];
        uint32_t u1 = xu[(size_t)s1 * 64 + lane];
        uint32_t u2 = xu[(size_t)s2 * 64 + lane];
        uint32_t u3 = xu[(size_t)s3 * 64 + lane];
        a0 += bflo(u0); a1 += bfhi(u0);
        b0 += bflo(u1); b1 += bfhi(u1);
        c0 += bflo(u2); c1 += bfhi(u2);
        d0 += bflo(u3); d1 += bfhi(u3);
    }
    for (; j < end; j++) {
        uint32_t u = xu[(size_t)csr[j] * 64 + lane];
        a0 += bflo(u); a1 += bfhi(u);
    }
    float sc = inv_deg[node];
    float r0 = ((a0 + b0) + (c0 + d0)) * sc, r1 = ((a1 + b1) + (c1 + d1)) * sc;
    outu[(size_t)node * 64 + lane] = (uint32_t)f2bf(r0) | ((uint32_t)f2bf(r1) << 16);
}

// final: out = mean_gather(t) + u, fp32 out
__global__ __launch_bounds__(256) void agg_final_128(const uint32_t* __restrict__ tu,
                                                     const int* __restrict__ row_start,
                                                     const int* __restrict__ deg,
                                                     const int* __restrict__ csr,
                                                     const float* __restrict__ inv_deg,
                                                     const float2* __restrict__ u,
                                                     float2* __restrict__ out) {
    int node = blockIdx.x * 4 + (threadIdx.x >> 6);
    int lane = threadIdx.x & 63;
    int beg = row_start[node], end = beg + deg[node];
    float a0 = 0.f, a1 = 0.f, b0 = 0.f, b1 = 0.f;
    float c0 = 0.f, c1 = 0.f, d0 = 0.f, d1 = 0.f;
    int j = beg;
    for (; j + 4 <= end; j += 4) {
        int s0 = csr[j], s1 = csr[j + 1], s2 = csr[j + 2], s3 = csr[j + 3];
        uint32_t u0 = tu[(size_t)s0 * 64 + lane];
        uint32_t u1 = tu[(size_t)s1 * 64 + lane];
        uint32_t u2 = tu[(size_t)s2 * 64 + lane];
        uint32_t u3 = tu[(size_t)s3 * 64 + lane];
        a0 += bflo(u0); a1 += bfhi(u0);
        b0 += bflo(u1); b1 += bfhi(u1);
        c0 += bflo(u2); c1 += bfhi(u2);
        d0 += bflo(u3); d1 += bfhi(u3);
    }
    for (; j < end; j++) {
        uint32_t uu = tu[(size_t)csr[j] * 64 + lane];
        a0 += bflo(uu); a1 += bfhi(uu);
    }
    float sc = inv_deg[node];
    float2 uv = u[(size_t)node * 64 + lane];
    float2 r;
    r.x = ((a0 + b0) + (c0 + d0)) * sc + uv.x;
    r.y = ((a1 + b1) + (c1 + d1)) * sc + uv.y;
    out[(size_t)node * 64 + lane] = r;
}

// ---------------- weight swizzle into B-fragment layout ----------------
__global__ __launch_bounds__(256) void swizzle_w(const uint16_t* __restrict__ W, uint16_t* __restrict__ Wsw,
                                                 int K, int N) {
    int t = blockIdx.x * 256 + threadIdx.x;
    int KT = K >> 5, NT = N >> 4;
    int tile = t >> 6, lane = t & 63;
    if (tile >= KT * NT) return;
    int kt = tile / NT, nt = tile - kt * NT;
    int n = lane & 15, q = lane >> 4;
    const uint16_t* s = W + (size_t)(kt * 32 + q * 8) * N + nt * 16 + n;
    uint16_t* d = Wsw + (size_t)tile * 512 + lane * 8;
#pragma unroll
    for (int j = 0; j < 8; j++) d[j] = s[(size_t)j * N];
}

// ---------------- layer-1 GEMM (dual-A, col-split, 64 rows/wave) ----------------
// block: 64 rows x N; wave w covers cols [w*N/4, (w+1)*N/4).
// Two sequential K-loops (one per operand) — no pointer arrays.
template <int K, int N>
__global__ __launch_bounds__(256) void gemm_dualA_cs(const uint16_t* __restrict__ A1,
                                                     const uint16_t* __restrict__ A2,
                                                     const uint16_t* __restrict__ W1sw,
                                                     const uint16_t* __restrict__ W2sw,
                                                     const uint16_t* __restrict__ bias,
                                                     uint16_t* __restrict__ C) {
    constexpr int NTF = N / 16;       // total col tiles
    constexpr int NTW = NTF / 4;      // col tiles per wave
    constexpr int KT = K / 32;
    int wave = threadIdx.x >> 6;
    int lane = threadIdx.x & 63;
    int row0 = blockIdx.x * 64;
    int bt = wave * NTW;
    int m = lane & 15, q = lane >> 4;

    int ar[4];
#pragma unroll
    for (int rf = 0; rf < 4; rf++) {
        int r = row0 + rf * 16 + m;
        ar[rf] = (r < NN) ? r : (NN - 1);
    }

    f32x4 acc[4][NTW];
#pragma unroll
    for (int rf = 0; rf < 4; rf++)
#pragma unroll
        for (int nt = 0; nt < NTW; nt++)
#pragma unroll
            for (int i = 0; i < 4; i++) acc[rf][nt][i] = 0.f;

    // operand 1: A1 @ W1
#pragma unroll
    for (int kt = 0; kt < KT; kt++) {
        bf16x8 a0 = *(const bf16x8*)(A1 + (size_t)ar[0] * K + kt * 32 + q * 8);
        bf16x8 a1 = *(const bf16x8*)(A1 + (size_t)ar[1] * K + kt * 32 + q * 8);
        bf16x8 a2 = *(const bf16x8*)(A1 + (size_t)ar[2] * K + kt * 32 + q * 8);
        bf16x8 a3 = *(const bf16x8*)(A1 + (size_t)ar[3] * K + kt * 32 + q * 8);
#pragma unroll
        for (int nt = 0; nt < NTW; nt++) {
            bf16x8 bfr = *(const bf16x8*)(W1sw + ((size_t)(kt * NTF + bt + nt)) * 512 + lane * 8);
            acc[0][nt] = __builtin_amdgcn_mfma_f32_16x16x32_bf16(a0, bfr, acc[0][nt], 0, 0, 0);
            acc[1][nt] = __builtin_amdgcn_mfma_f32_16x16x32_bf16(a1, bfr, acc[1][nt], 0, 0, 0);
            acc[2][nt] = __builtin_amdgcn_mfma_f32_16x16x32_bf16(a2, bfr, acc[2][nt], 0, 0, 0);
            acc[3][nt] = __builtin_amdgcn_mfma_f32_16x16x32_bf16(a3, bfr, acc[3][nt], 0, 0, 0);
        }
    }
    // operand 2: A2 @ W2
#pragma unroll
    for (int kt = 0; kt < KT; kt++) {
        bf16x8 a0 = *(const bf16x8*)(A2 + (size_t)ar[0] * K + kt * 32 + q * 8);
        bf16x8 a1 = *(const bf16x8*)(A2 + (size_t)ar[1] * K + kt * 32 + q * 8);
        bf16x8 a2 = *(const bf16x8*)(A2 + (size_t)ar[2] * K + kt * 32 + q * 8);
        bf16x8 a3 = *(const bf16x8*)(A2 + (size_t)ar[3] * K + kt * 32 + q * 8);
#pragma unroll
        for (int nt = 0; nt < NTW; nt++) {
            bf16x8 bfr = *(const bf16x8*)(W2sw + ((size_t)(kt * NTF + bt + nt)) * 512 + lane * 8);
            acc[0][nt] = __builtin_amdgcn_mfma_f32_16x16x32_bf16(a0, bfr, acc[0][nt], 0, 0, 0);
            acc[1][nt] = __builtin_amdgcn_mfma_f32_16x16x32_bf16(a1, bfr, acc[1][nt], 0, 0, 0);
            acc[2][nt] = __builtin_amdgcn_mfma_f32_16x16x32_bf16(a2, bfr, acc[2][nt], 0, 0, 0);
            acc[3][nt] = __builtin_amdgcn_mfma_f32_16x16x32_bf16(a3, bfr, acc[3][nt], 0, 0, 0);
        }
    }

#pragma unroll
    for (int nt = 0; nt < NTW; nt++) {
        int col = (bt + nt) * 16 + m;
        float bv = bf2f(bias[col]);
#pragma unroll
        for (int rf = 0; rf < 4; rf++)
#pragma unroll
            for (int i = 0; i < 4; i++) {
                int r = row0 + rf * 16 + q * 4 + i;
                if (r < NN) {
                    float v = fmaxf(acc[rf][nt][i] + bv, 0.f);
                    C[(size_t)r * N + col] = f2bf(v);
                }
            }
    }
}

// ---------------- layer-2 GEMM (dual-B, col-split, 64 rows/wave) ----------------
// t = A@W1 (bf16), u = A@W2 + bias (fp32)
template <int K, int N>
__global__ __launch_bounds__(256) void gemm_dualB_cs(const uint16_t* __restrict__ A,
                                                     const uint16_t* __restrict__ W1sw,
                                                     const uint16_t* __restrict__ W2sw,
                                                     const uint16_t* __restrict__ bias,
                                                     uint16_t* __restrict__ T,
                                                     float* __restrict__ U) {
    constexpr int NTF = N / 16;
    constexpr int NTW = NTF / 4;
    constexpr int KT = K / 32;
    int wave = threadIdx.x >> 6;
    int lane = threadIdx.x & 63;
    int row0 = blockIdx.x * 64;
    int bt = wave * NTW;
    int m = lane & 15, q = lane >> 4;

    int ar[4];
#pragma unroll
    for (int rf = 0; rf < 4; rf++) {
        int r = row0 + rf * 16 + m;
        ar[rf] = (r < NN) ? r : (NN - 1);
    }

    f32x4 acc1[4][NTW], acc2[4][NTW];
#pragma unroll
    for (int rf = 0; rf < 4; rf++)
#pragma unroll
        for (int nt = 0; nt < NTW; nt++)
#pragma unroll
            for (int i = 0; i < 4; i++) { acc1[rf][nt][i] = 0.f; acc2[rf][nt][i] = 0.f; }

#pragma unroll
    for (int kt = 0; kt < KT; kt++) {
        bf16x8 a0 = *(const bf16x8*)(A + (size_t)ar[0] * K + kt * 32 + q * 8);
        bf16x8 a1 = *(const bf16x8*)(A + (size_t)ar[1] * K + kt * 32 + q * 8);
        bf16x8 a2 = *(const bf16x8*)(A + (size_t)ar[2] * K + kt * 32 + q * 8);
        bf16x8 a3 = *(const bf16x8*)(A + (size_t)ar[3] * K + kt * 32 + q * 8);
#pragma unroll
        for (int nt = 0; nt < NTW; nt++) {
            bf16x8 b1 = *(const bf16x8*)(W1sw + ((size_t)(kt * NTF + bt + nt)) * 512 + lane * 8);
            acc1[0][nt] = __builtin_amdgcn_mfma_f32_16x16x32_bf16(a0, b1, acc1[0][nt], 0, 0, 0);
            acc1[1][nt] = __builtin_amdgcn_mfma_f32_16x16x32_bf16(a1, b1, acc1[1][nt], 0, 0, 0);
            acc1[2][nt] = __builtin_amdgcn_mfma_f32_16x16x32_bf16(a2, b1, acc1[2][nt], 0, 0, 0);
            acc1[3][nt] = __builtin_amdgcn_mfma_f32_16x16x32_bf16(a3, b1, acc1[3][nt], 0, 0, 0);
            bf16x8 b2 = *(const bf16x8*)(W2sw + ((size_t)(kt * NTF + bt + nt)) * 512 + lane * 8);
            acc2[0][nt] = __builtin_amdgcn_mfma_f32_16x16x32_bf16(a0, b2, acc2[0][nt], 0, 0, 0);
            acc2[1][nt] = __builtin_amdgcn_mfma_f32_16x16x32_bf16(a1, b2, acc2[1][nt], 0, 0, 0);
            acc2[2][nt] = __builtin_amdgcn_mfma_f32_16x16x32_bf16(a2, b2, acc2[2][nt], 0, 0, 0);
            acc2[3][nt] = __builtin_amdgcn_mfma_f32_16x16x32_bf16(a3, b2, acc2[3][nt], 0, 0, 0);
        }
    }

#pragma unroll
    for (int nt = 0; nt < NTW; nt++) {
        int col = (bt + nt) * 16 + m;
        float bv = bf2f(bias[col]);
#pragma unroll
        for (int rf = 0; rf < 4; rf++)
#pragma unroll
            for (int i = 0; i < 4; i++) {
                int r = row0 + rf * 16 + q * 4 + i;
                if (r < NN) {
                    T[(size_t)r * N + col] = f2bf(acc1[rf][nt][i]);
                    U[(size_t)r * N + col] = acc2[rf][nt][i] + bv;
                }
            }
    }
}

extern "C" void kernel_launch(void* const* d_in, const int* in_sizes, int n_in,
                              void* d_out, int out_size, void* d_ws, size_t ws_size,
                              hipStream_t stream) {
    const void* x_raw  = d_in[0];
    const int*  ei     = (const int*)d_in[1];
    const void* W1l    = d_in[2];
    const void* b1     = d_in[3];
    const void* W1r    = d_in[4];
    const void* W2l    = d_in[5];
    const void* b2     = d_in[6];
    const void* W2r    = d_in[7];

    uint8_t* ws = (uint8_t*)d_ws;
    size_t off = 0;
    auto alloc = [&](size_t b) -> void* {
        void* p = ws + off;
        off += (b + 255) & ~(size_t)255;
        return p;
    };
    int*      flags     = (int*)alloc(256);
    int*      counter   = (int*)alloc(256);
    int*      deg       = (int*)alloc((size_t)NN * 4);
    float*    inv_deg   = (float*)alloc((size_t)NN * 4);
    int*      row_start = (int*)alloc((size_t)NN * 4);
    int*      cursor    = (int*)alloc((size_t)NN * 4);
    int*      srcn      = (int*)alloc((size_t)NE * 4);
    int*      dstn      = (int*)alloc((size_t)NE * 4);
    int*      csr       = (int*)alloc((size_t)NE * 4);
    uint32_t* xb        = (uint32_t*)alloc((size_t)NN * 64 * 4);
    uint32_t* wbuf      = (uint32_t*)alloc(65728 * 4);
    uint16_t* agg       = (uint16_t*)alloc((size_t)NN * 128 * 2);
    uint16_t* h         = (uint16_t*)alloc((size_t)NN * 256 * 2);
    uint16_t* t         = (uint16_t*)alloc((size_t)NN * 128 * 2);
    float*    u         = (float*)alloc((size_t)NN * 128 * 4);
    uint16_t* w1l_sw    = (uint16_t*)alloc(128 * 256 * 2);
    uint16_t* w1r_sw    = (uint16_t*)alloc(128 * 256 * 2);
    uint16_t* w2l_sw    = (uint16_t*)alloc(256 * 128 * 2);
    uint16_t* w2r_sw    = (uint16_t*)alloc(256 * 128 * 2);

    uint16_t* wb      = (uint16_t*)wbuf;
    uint16_t* w1l_n   = wb + 0;
    uint16_t* b1_n    = wb + 32768;
    uint16_t* w1r_n   = wb + 33024;
    uint16_t* w2l_n   = wb + 65792;
    uint16_t* b2_n    = wb + 98560;
    uint16_t* w2r_n   = wb + 98688;

    detect<<<1, 256, 0, stream>>>((const uint32_t*)x_raw, ei, flags);
    hipMemsetAsync(counter, 0, 256, stream);
    hipMemsetAsync(deg, 0, (size_t)NN * 4, stream);

    norm_edges_count<<<(NE + 255) / 256, 256, 0, stream>>>(ei, flags, srcn, dstn, deg);
    norm_x<<<(NN * 64 + 255) / 256, 256, 0, stream>>>(x_raw, flags, xb);
    norm_weights<<<257, 256, 0, stream>>>(W1l, b1, W1r, W2l, b2, W2r, flags, wbuf);

    alloc_rows<<<(NN + 255) / 256, 256, 0, stream>>>(deg, counter, row_start, cursor, inv_deg);
    fill_csr<<<(NE + 255) / 256, 256, 0, stream>>>(srcn, dstn, cursor, csr);

    swizzle_w<<<16, 256, 0, stream>>>(w1l_n, w1l_sw, 128, 256);
    swizzle_w<<<16, 256, 0, stream>>>(w1r_n, w1r_sw, 128, 256);
    swizzle_w<<<16, 256, 0, stream>>>(w2l_n, w2l_sw, 256, 128);
    swizzle_w<<<16, 256, 0, stream>>>(w2r_n, w2r_sw, 256, 128);

    // layer 1: agg = A·x ; h = relu(agg@W1l + x@W1r + b1)
    agg_mean_128<<<NN / 4, 256, 0, stream>>>(xb, row_start, deg, csr, inv_deg, (uint32_t*)agg);
    gemm_dualA_cs<128, 256><<<(NN + 63) / 64, 256, 0, stream>>>(agg, (const uint16_t*)xb, w1l_sw, w1r_sw, b1_n, h);
    // layer 2: t = h@W2l, u = h@W2r + b2 ; out = A·t + u
    gemm_dualB_cs<256, 128><<<(NN + 63) / 64, 256, 0, stream>>>(h, w2l_sw, w2r_sw, b2_n, t, u);
    agg_final_128<<<NN / 4, 256, 0, stream>>>((const uint32_t*)t, row_start, deg, csr, inv_deg,
                                              (const float2*)u, (float2*)d_out);
}

// Round 8
// 349.653 us; speedup vs baseline: 1.3447x; 1.0015x over previous
//
#include <hip/hip_runtime.h>
#include <hip/hip_bf16.h>
#include <stdint.h>

#define NN 50000
#define NE 800000
#define NB 196            // dst buckets: dst>>8, 256 nodes each
#define EPB 2048          // edges per block in edge-pass kernels
#define NBLK ((NE + EPB - 1) / EPB)   // 391

typedef __attribute__((ext_vector_type(8))) __bf16 bf16x8;
typedef __attribute__((ext_vector_type(4))) float f32x4;

__device__ __forceinline__ float bflo(uint32_t u) { return __uint_as_float(u << 16); }
__device__ __forceinline__ float bfhi(uint32_t u) { return __uint_as_float(u & 0xffff0000u); }
__device__ __forceinline__ uint16_t f2bf(float f) {
    uint32_t u = __float_as_uint(f);
    u += 0x7fffu + ((u >> 16) & 1u);   // RNE
    return (uint16_t)(u >> 16);
}
__device__ __forceinline__ float bf2f(uint16_t h) { return __uint_as_float(((uint32_t)h) << 16); }

// ---------------- dtype detection (insurance) ----------------
__global__ __launch_bounds__(256) void detect(const uint32_t* __restrict__ xu,
                                              const int* __restrict__ ei,
                                              int* __restrict__ flags) {
    __shared__ int cnt_f, cnt_i;
    if (threadIdx.x == 0) { cnt_f = 0; cnt_i = 0; }
    __syncthreads();
    uint32_t u = xu[threadIdx.x];
    uint32_t lo = u & 0xffffu;
    uint32_t e = (lo >> 7) & 0xffu;
    int ok = (lo == 0u) || (e >= 96u && e <= 150u);
    atomicAdd(&cnt_f, ok);
    if (threadIdx.x < 64) {
        int w = ei[2 * threadIdx.x + 1];
        atomicAdd(&cnt_i, (w != 0) ? 1 : 0);
    }
    __syncthreads();
    if (threadIdx.x == 0) {
        flags[0] = (cnt_f < 192) ? 1 : 0;
        flags[1] = (cnt_i < 4) ? 1 : 0;
    }
}

// ---------------- edge normalize + degree count + bucket histogram ----------------
__global__ __launch_bounds__(256) void norm_edges_count(const int* __restrict__ ei, const int* __restrict__ flags,
                                                        int* __restrict__ src, int* __restrict__ dst,
                                                        int* __restrict__ deg, int* __restrict__ bucket_cnt) {
    __shared__ int hist[NB];
    for (int t = threadIdx.x; t < NB; t += 256) hist[t] = 0;
    __syncthreads();
    int base = blockIdx.x * EPB;
    int fl = flags[1];
    for (int i = 0; i < EPB; i += 256) {
        int e = base + i + threadIdx.x;
        if (e < NE) {
            int s, d;
            if (fl) { s = ei[2 * e]; d = ei[2 * NE + 2 * e]; }
            else    { s = ei[e];     d = ei[NE + e]; }
            src[e] = s;
            dst[e] = d;
            atomicAdd(&deg[d], 1);
            atomicAdd(&hist[d >> 8], 1);
        }
    }
    __syncthreads();
    for (int t = threadIdx.x; t < NB; t += 256) {
        int c = hist[t];
        if (c) atomicAdd(&bucket_cnt[t], c);
    }
}

__global__ __launch_bounds__(256) void norm_x(const void* __restrict__ x, const int* __restrict__ flags,
                                              uint32_t* __restrict__ out) {
    int i = blockIdx.x * 256 + threadIdx.x;  // < NN*64
    if (flags[0]) {
        float2 v = ((const float2*)x)[i];
        out[i] = (uint32_t)f2bf(v.x) | ((uint32_t)f2bf(v.y) << 16);
    } else {
        out[i] = ((const uint32_t*)x)[i];
    }
}

__global__ __launch_bounds__(256) void norm_weights(const void* __restrict__ w1l, const void* __restrict__ b1,
                                                    const void* __restrict__ w1r, const void* __restrict__ w2l,
                                                    const void* __restrict__ b2, const void* __restrict__ w2r,
                                                    const int* __restrict__ flags, uint32_t* __restrict__ out) {
    constexpr int off[7] = {0, 16384, 16512, 32896, 49280, 49344, 65728};  // pair offsets
    int i = blockIdx.x * 256 + threadIdx.x;
    if (i >= 65728) return;
    int t = 0;
    while (i >= off[t + 1]) t++;
    const void* srcs[6] = {w1l, b1, w1r, w2l, b2, w2r};
    int j = i - off[t];
    uint32_t r;
    if (flags[0]) {
        float2 v = ((const float2*)srcs[t])[j];
        r = (uint32_t)f2bf(v.x) | ((uint32_t)f2bf(v.y) << 16);
    } else {
        r = ((const uint32_t*)srcs[t])[j];
    }
    out[i] = r;
}

// ---------------- bucket scan (196 values, 1 block) ----------------
__global__ __launch_bounds__(256) void scan_buckets(const int* __restrict__ bucket_cnt,
                                                    int* __restrict__ bucket_base,
                                                    int* __restrict__ bucket_cursor) {
    __shared__ int sm[256];
    int t = threadIdx.x;
    int v = (t < NB) ? bucket_cnt[t] : 0;
    sm[t] = v;
    __syncthreads();
    for (int o = 1; o < 256; o <<= 1) {
        int x = (t >= o) ? sm[t - o] : 0;
        __syncthreads();
        sm[t] += x;
        __syncthreads();
    }
    if (t < NB) {
        int excl = sm[t] - v;
        bucket_base[t] = excl;
        bucket_cursor[t] = excl;
    }
    if (t == 0) bucket_base[NB] = NE;
}

// ---------------- CSR segment allocation (order-free) ----------------
__global__ __launch_bounds__(256) void alloc_rows(const int* __restrict__ deg, int* __restrict__ counter,
                                                  int* __restrict__ row_start, int* __restrict__ cursor,
                                                  float* __restrict__ inv_deg) {
    int node = blockIdx.x * 256 + threadIdx.x;
    int lane = threadIdx.x & 63;
    int d = (node < NN) ? deg[node] : 0;
    int incl = d;
#pragma unroll
    for (int o = 1; o < 64; o <<= 1) {
        int t = __shfl_up(incl, o, 64);
        if (lane >= o) incl += t;
    }
    int excl = incl - d;
    int wave_total = __shfl(incl, 63, 64);
    int base = 0;
    if (lane == 63) base = atomicAdd(counter, wave_total);
    base = __shfl(base, 63, 64);
    if (node < NN) {
        int rs = base + excl;
        row_start[node] = rs;
        cursor[node] = rs;
        inv_deg[node] = 1.0f / (float)(d > 0 ? d : 1);
    }
}

// ---------------- bin edges bucket-major into staging ----------------
__global__ __launch_bounds__(256) void bin_edges(const int* __restrict__ src, const int* __restrict__ dst,
                                                 int* __restrict__ bucket_cursor, uint2* __restrict__ staging) {
    __shared__ int hist[NB];
    __shared__ int curs[NB];
    for (int t = threadIdx.x; t < NB; t += 256) hist[t] = 0;
    __syncthreads();
    int base = blockIdx.x * EPB;
    for (int i = 0; i < EPB; i += 256) {
        int e = base + i + threadIdx.x;
        if (e < NE) atomicAdd(&hist[dst[e] >> 8], 1);
    }
    __syncthreads();
    for (int t = threadIdx.x; t < NB; t += 256) {
        int c = hist[t];
        curs[t] = c ? atomicAdd(&bucket_cursor[t], c) : 0;
    }
    __syncthreads();
    for (int i = 0; i < EPB; i += 256) {
        int e = base + i + threadIdx.x;
        if (e < NE) {
            int d = dst[e];
            int p = atomicAdd(&curs[d >> 8], 1);
            uint2 v;
            v.x = (unsigned)src[e];
            v.y = (unsigned)d;
            staging[p] = v;
        }
    }
}

// ---------------- CSR fill, one block per bucket (L2-local scatter) ----------------
__global__ __launch_bounds__(256) void fill_csr_binned(const uint2* __restrict__ staging,
                                                       const int* __restrict__ bucket_base,
                                                       int* __restrict__ cursor, int* __restrict__ csr) {
    int b = blockIdx.x;
    int beg = bucket_base[b], end = bucket_base[b + 1];
    for (int e = beg + threadIdx.x; e < end; e += 256) {
        uint2 v = staging[e];
        int pos = atomicAdd(&cursor[v.y], 1);
        csr[pos] = (int)v.x;
    }
}

// ---------------- mean aggregation over 128-wide packed bf16 ----------------
__global__ __launch_bounds__(256) void agg_mean_128(const uint32_t* __restrict__ xu,
                                                    const int* __restrict__ row_start,
                                                    const int* __restrict__ deg,
                                                    const int* __restrict__ csr,
                                                    const float* __restrict__ inv_deg,
                                                    uint32_t* __restrict__ outu) {
    int node = blockIdx.x * 4 + (threadIdx.x >> 6);
    int lane = threadIdx.x & 63;
    int beg = row_start[node], end = beg + deg[node];
    float a0 = 0.f, a1 = 0.f, b0 = 0.f, b1 = 0.f;
    float c0 = 0.f, c1 = 0.f, d0 = 0.f, d1 = 0.f;
    int j = beg;
    for (; j + 4 <= end; j += 4) {
        int s0 = csr[j], s1 = csr[j + 1], s2 = csr[j + 2], s3 = csr[j + 3];
        uint32_t u0 = xu[(size_t)s0 * 64 + lane];
        uint32_t u1 = xu[(size_t)s1 * 64 + lane];
        uint32_t u2 = xu[(size_t)s2 * 64 + lane];
        uint32_t u3 = xu[(size_t)s3 * 64 + lane];
        a0 += bflo(u0); a1 += bfhi(u0);
        b0 += bflo(u1); b1 += bfhi(u1);
        c0 += bflo(u2); c1 += bfhi(u2);
        d0 += bflo(u3); d1 += bfhi(u3);
    }
    for (; j < end; j++) {
        uint32_t u = xu[(size_t)csr[j] * 64 + lane];
        a0 += bflo(u); a1 += bfhi(u);
    }
    float sc = inv_deg[node];
    float r0 = ((a0 + b0) + (c0 + d0)) * sc, r1 = ((a1 + b1) + (c1 + d1)) * sc;
    outu[(size_t)node * 64 + lane] = (uint32_t)f2bf(r0) | ((uint32_t)f2bf(r1) << 16);
}

// final: out = mean_gather(t) + u, fp32 out
__global__ __launch_bounds__(256) void agg_final_128(const uint32_t* __restrict__ tu,
                                                     const int* __restrict__ row_start,
                                                     const int* __restrict__ deg,
                                                     const int* __restrict__ csr,
                                                     const float* __restrict__ inv_deg,
                                                     const float2* __restrict__ u,
                                                     float2* __restrict__ out) {
    int node = blockIdx.x * 4 + (threadIdx.x >> 6);
    int lane = threadIdx.x & 63;
    int beg = row_start[node], end = beg + deg[node];
    float a0 = 0.f, a1 = 0.f, b0 = 0.f, b1 = 0.f;
    float c0 = 0.f, c1 = 0.f, d0 = 0.f, d1 = 0.f;
    int j = beg;
    for (; j + 4 <= end; j += 4) {
        int s0 = csr[j], s1 = csr[j + 1], s2 = csr[j + 2], s3 = csr[j + 3];
        uint32_t u0 = tu[(size_t)s0 * 64 + lane];
        uint32_t u1 = tu[(size_t)s1 * 64 + lane];
        uint32_t u2 = tu[(size_t)s2 * 64 + lane];
        uint32_t u3 = tu[(size_t)s3 * 64 + lane];
        a0 += bflo(u0); a1 += bfhi(u0);
        b0 += bflo(u1); b1 += bfhi(u1);
        c0 += bflo(u2); c1 += bfhi(u2);
        d0 += bflo(u3); d1 += bfhi(u3);
    }
    for (; j < end; j++) {
        uint32_t uu = tu[(size_t)csr[j] * 64 + lane];
        a0 += bflo(uu); a1 += bfhi(uu);
    }
    float sc = inv_deg[node];
    float2 uv = u[(size_t)node * 64 + lane];
    float2 r;
    r.x = ((a0 + b0) + (c0 + d0)) * sc + uv.x;
    r.y = ((a1 + b1) + (c1 + d1)) * sc + uv.y;
    out[(size_t)node * 64 + lane] = r;
}

// ---------------- weight swizzle into B-fragment layout ----------------
__global__ __launch_bounds__(256) void swizzle_w(const uint16_t* __restrict__ W, uint16_t* __restrict__ Wsw,
                                                 int K, int N) {
    int t = blockIdx.x * 256 + threadIdx.x;
    int KT = K >> 5, NT = N >> 4;
    int tile = t >> 6, lane = t & 63;
    if (tile >= KT * NT) return;
    int kt = tile / NT, nt = tile - kt * NT;
    int n = lane & 15, q = lane >> 4;
    const uint16_t* s = W + (size_t)(kt * 32 + q * 8) * N + nt * 16 + n;
    uint16_t* d = Wsw + (size_t)tile * 512 + lane * 8;
#pragma unroll
    for (int j = 0; j < 8; j++) d[j] = s[(size_t)j * N];
}

// ---------------- layer-1 GEMM (dual-A, col-split, 64 rows/wave) ----------------
template <int K, int N>
__global__ __launch_bounds__(256) void gemm_dualA_cs(const uint16_t* __restrict__ A1,
                                                     const uint16_t* __restrict__ A2,
                                                     const uint16_t* __restrict__ W1sw,
                                                     const uint16_t* __restrict__ W2sw,
                                                     const uint16_t* __restrict__ bias,
                                                     uint16_t* __restrict__ C) {
    constexpr int NTF = N / 16;
    constexpr int NTW = NTF / 4;
    constexpr int KT = K / 32;
    int wave = threadIdx.x >> 6;
    int lane = threadIdx.x & 63;
    int row0 = blockIdx.x * 64;
    int bt = wave * NTW;
    int m = lane & 15, q = lane >> 4;

    int ar[4];
#pragma unroll
    for (int rf = 0; rf < 4; rf++) {
        int r = row0 + rf * 16 + m;
        ar[rf] = (r < NN) ? r : (NN - 1);
    }

    f32x4 acc[4][NTW];
#pragma unroll
    for (int rf = 0; rf < 4; rf++)
#pragma unroll
        for (int nt = 0; nt < NTW; nt++)
#pragma unroll
            for (int i = 0; i < 4; i++) acc[rf][nt][i] = 0.f;

#pragma unroll
    for (int kt = 0; kt < KT; kt++) {
        bf16x8 a0 = *(const bf16x8*)(A1 + (size_t)ar[0] * K + kt * 32 + q * 8);
        bf16x8 a1 = *(const bf16x8*)(A1 + (size_t)ar[1] * K + kt * 32 + q * 8);
        bf16x8 a2 = *(const bf16x8*)(A1 + (size_t)ar[2] * K + kt * 32 + q * 8);
        bf16x8 a3 = *(const bf16x8*)(A1 + (size_t)ar[3] * K + kt * 32 + q * 8);
#pragma unroll
        for (int nt = 0; nt < NTW; nt++) {
            bf16x8 bfr = *(const bf16x8*)(W1sw + ((size_t)(kt * NTF + bt + nt)) * 512 + lane * 8);
            acc[0][nt] = __builtin_amdgcn_mfma_f32_16x16x32_bf16(a0, bfr, acc[0][nt], 0, 0, 0);
            acc[1][nt] = __builtin_amdgcn_mfma_f32_16x16x32_bf16(a1, bfr, acc[1][nt], 0, 0, 0);
            acc[2][nt] = __builtin_amdgcn_mfma_f32_16x16x32_bf16(a2, bfr, acc[2][nt], 0, 0, 0);
            acc[3][nt] = __builtin_amdgcn_mfma_f32_16x16x32_bf16(a3, bfr, acc[3][nt], 0, 0, 0);
        }
    }
#pragma unroll
    for (int kt = 0; kt < KT; kt++) {
        bf16x8 a0 = *(const bf16x8*)(A2 + (size_t)ar[0] * K + kt * 32 + q * 8);
        bf16x8 a1 = *(const bf16x8*)(A2 + (size_t)ar[1] * K + kt * 32 + q * 8);
        bf16x8 a2 = *(const bf16x8*)(A2 + (size_t)ar[2] * K + kt * 32 + q * 8);
        bf16x8 a3 = *(const bf16x8*)(A2 + (size_t)ar[3] * K + kt * 32 + q * 8);
#pragma unroll
        for (int nt = 0; nt < NTW; nt++) {
            bf16x8 bfr = *(const bf16x8*)(W2sw + ((size_t)(kt * NTF + bt + nt)) * 512 + lane * 8);
            acc[0][nt] = __builtin_amdgcn_mfma_f32_16x16x32_bf16(a0, bfr, acc[0][nt], 0, 0, 0);
            acc[1][nt] = __builtin_amdgcn_mfma_f32_16x16x32_bf16(a1, bfr, acc[1][nt], 0, 0, 0);
            acc[2][nt] = __builtin_amdgcn_mfma_f32_16x16x32_bf16(a2, bfr, acc[2][nt], 0, 0, 0);
            acc[3][nt] = __builtin_amdgcn_mfma_f32_16x16x32_bf16(a3, bfr, acc[3][nt], 0, 0, 0);
        }
    }

#pragma unroll
    for (int nt = 0; nt < NTW; nt++) {
        int col = (bt + nt) * 16 + m;
        float bv = bf2f(bias[col]);
#pragma unroll
        for (int rf = 0; rf < 4; rf++)
#pragma unroll
            for (int i = 0; i < 4; i++) {
                int r = row0 + rf * 16 + q * 4 + i;
                if (r < NN) {
                    float v = fmaxf(acc[rf][nt][i] + bv, 0.f);
                    C[(size_t)r * N + col] = f2bf(v);
                }
            }
    }
}

// ---------------- layer-2 GEMM (dual-B, col-split, 64 rows/wave) ----------------
template <int K, int N>
__global__ __launch_bounds__(256) void gemm_dualB_cs(const uint16_t* __restrict__ A,
                                                     const uint16_t* __restrict__ W1sw,
                                                     const uint16_t* __restrict__ W2sw,
                                                     const uint16_t* __restrict__ bias,
                                                     uint16_t* __restrict__ T,
                                                     float* __restrict__ U) {
    constexpr int NTF = N / 16;
    constexpr int NTW = NTF / 4;
    constexpr int KT = K / 32;
    int wave = threadIdx.x >> 6;
    int lane = threadIdx.x & 63;
    int row0 = blockIdx.x * 64;
    int bt = wave * NTW;
    int m = lane & 15, q = lane >> 4;

    int ar[4];
#pragma unroll
    for (int rf = 0; rf < 4; rf++) {
        int r = row0 + rf * 16 + m;
        ar[rf] = (r < NN) ? r : (NN - 1);
    }

    f32x4 acc1[4][NTW], acc2[4][NTW];
#pragma unroll
    for (int rf = 0; rf < 4; rf++)
#pragma unroll
        for (int nt = 0; nt < NTW; nt++)
#pragma unroll
            for (int i = 0; i < 4; i++) { acc1[rf][nt][i] = 0.f; acc2[rf][nt][i] = 0.f; }

#pragma unroll
    for (int kt = 0; kt < KT; kt++) {
        bf16x8 a0 = *(const bf16x8*)(A + (size_t)ar[0] * K + kt * 32 + q * 8);
        bf16x8 a1 = *(const bf16x8*)(A + (size_t)ar[1] * K + kt * 32 + q * 8);
        bf16x8 a2 = *(const bf16x8*)(A + (size_t)ar[2] * K + kt * 32 + q * 8);
        bf16x8 a3 = *(const bf16x8*)(A + (size_t)ar[3] * K + kt * 32 + q * 8);
#pragma unroll
        for (int nt = 0; nt < NTW; nt++) {
            bf16x8 b1 = *(const bf16x8*)(W1sw + ((size_t)(kt * NTF + bt + nt)) * 512 + lane * 8);
            acc1[0][nt] = __builtin_amdgcn_mfma_f32_16x16x32_bf16(a0, b1, acc1[0][nt], 0, 0, 0);
            acc1[1][nt] = __builtin_amdgcn_mfma_f32_16x16x32_bf16(a1, b1, acc1[1][nt], 0, 0, 0);
            acc1[2][nt] = __builtin_amdgcn_mfma_f32_16x16x32_bf16(a2, b1, acc1[2][nt], 0, 0, 0);
            acc1[3][nt] = __builtin_amdgcn_mfma_f32_16x16x32_bf16(a3, b1, acc1[3][nt], 0, 0, 0);
            bf16x8 b2 = *(const bf16x8*)(W2sw + ((size_t)(kt * NTF + bt + nt)) * 512 + lane * 8);
            acc2[0][nt] = __builtin_amdgcn_mfma_f32_16x16x32_bf16(a0, b2, acc2[0][nt], 0, 0, 0);
            acc2[1][nt] = __builtin_amdgcn_mfma_f32_16x16x32_bf16(a1, b2, acc2[1][nt], 0, 0, 0);
            acc2[2][nt] = __builtin_amdgcn_mfma_f32_16x16x32_bf16(a2, b2, acc2[2][nt], 0, 0, 0);
            acc2[3][nt] = __builtin_amdgcn_mfma_f32_16x16x32_bf16(a3, b2, acc2[3][nt], 0, 0, 0);
        }
    }

#pragma unroll
    for (int nt = 0; nt < NTW; nt++) {
        int col = (bt + nt) * 16 + m;
        float bv = bf2f(bias[col]);
#pragma unroll
        for (int rf = 0; rf < 4; rf++)
#pragma unroll
            for (int i = 0; i < 4; i++) {
                int r = row0 + rf * 16 + q * 4 + i;
                if (r < NN) {
                    T[(size_t)r * N + col] = f2bf(acc1[rf][nt][i]);
                    U[(size_t)r * N + col] = acc2[rf][nt][i] + bv;
                }
            }
    }
}

extern "C" void kernel_launch(void* const* d_in, const int* in_sizes, int n_in,
                              void* d_out, int out_size, void* d_ws, size_t ws_size,
                              hipStream_t stream) {
    const void* x_raw  = d_in[0];
    const int*  ei     = (const int*)d_in[1];
    const void* W1l    = d_in[2];
    const void* b1     = d_in[3];
    const void* W1r    = d_in[4];
    const void* W2l    = d_in[5];
    const void* b2     = d_in[6];
    const void* W2r    = d_in[7];

    uint8_t* ws = (uint8_t*)d_ws;
    size_t off = 0;
    auto alloc = [&](size_t b) -> void* {
        void* p = ws + off;
        off += (b + 255) & ~(size_t)255;
        return p;
    };
    int*      flags      = (int*)alloc(256);
    int*      counter    = (int*)alloc(256);
    int*      bucket_cnt = (int*)alloc((NB + 1) * 4);
    int*      bucket_base= (int*)alloc((NB + 1) * 4);
    int*      bucket_cur = (int*)alloc((NB + 1) * 4);
    int*      deg        = (int*)alloc((size_t)NN * 4);
    float*    inv_deg    = (float*)alloc((size_t)NN * 4);
    int*      row_start  = (int*)alloc((size_t)NN * 4);
    int*      cursor     = (int*)alloc((size_t)NN * 4);
    int*      srcn       = (int*)alloc((size_t)NE * 4);
    int*      dstn       = (int*)alloc((size_t)NE * 4);
    int*      csr        = (int*)alloc((size_t)NE * 4);
    uint32_t* xb         = (uint32_t*)alloc((size_t)NN * 64 * 4);
    uint32_t* wbuf       = (uint32_t*)alloc(65728 * 4);
    uint16_t* agg        = (uint16_t*)alloc((size_t)NN * 128 * 2);
    uint16_t* h          = (uint16_t*)alloc((size_t)NN * 256 * 2);
    uint16_t* t          = (uint16_t*)alloc((size_t)NN * 128 * 2);
    float*    u          = (float*)alloc((size_t)NN * 128 * 4);
    uint16_t* w1l_sw     = (uint16_t*)alloc(128 * 256 * 2);
    uint16_t* w1r_sw     = (uint16_t*)alloc(128 * 256 * 2);
    uint16_t* w2l_sw     = (uint16_t*)alloc(256 * 128 * 2);
    uint16_t* w2r_sw     = (uint16_t*)alloc(256 * 128 * 2);

    // staging aliases h (used strictly before h is written)
    uint2* staging = (uint2*)h;

    uint16_t* wb      = (uint16_t*)wbuf;
    uint16_t* w1l_n   = wb + 0;
    uint16_t* b1_n    = wb + 32768;
    uint16_t* w1r_n   = wb + 33024;
    uint16_t* w2l_n   = wb + 65792;
    uint16_t* b2_n    = wb + 98560;
    uint16_t* w2r_n   = wb + 98688;

    detect<<<1, 256, 0, stream>>>((const uint32_t*)x_raw, ei, flags);
    hipMemsetAsync(counter, 0, 256, stream);
    hipMemsetAsync(bucket_cnt, 0, (NB + 1) * 4, stream);
    hipMemsetAsync(deg, 0, (size_t)NN * 4, stream);

    norm_edges_count<<<NBLK, 256, 0, stream>>>(ei, flags, srcn, dstn, deg, bucket_cnt);
    norm_x<<<(NN * 64 + 255) / 256, 256, 0, stream>>>(x_raw, flags, xb);
    norm_weights<<<257, 256, 0, stream>>>(W1l, b1, W1r, W2l, b2, W2r, flags, wbuf);

    scan_buckets<<<1, 256, 0, stream>>>(bucket_cnt, bucket_base, bucket_cur);
    alloc_rows<<<(NN + 255) / 256, 256, 0, stream>>>(deg, counter, row_start, cursor, inv_deg);
    bin_edges<<<NBLK, 256, 0, stream>>>(srcn, dstn, bucket_cur, staging);
    fill_csr_binned<<<NB, 256, 0, stream>>>(staging, bucket_base, cursor, csr);

    swizzle_w<<<16, 256, 0, stream>>>(w1l_n, w1l_sw, 128, 256);
    swizzle_w<<<16, 256, 0, stream>>>(w1r_n, w1r_sw, 128, 256);
    swizzle_w<<<16, 256, 0, stream>>>(w2l_n, w2l_sw, 256, 128);
    swizzle_w<<<16, 256, 0, stream>>>(w2r_n, w2r_sw, 256, 128);

    // layer 1: agg = A·x ; h = relu(agg@W1l + x@W1r + b1)
    agg_mean_128<<<NN / 4, 256, 0, stream>>>(xb, row_start, deg, csr, inv_deg, (uint32_t*)agg);
    gemm_dualA_cs<128, 256><<<(NN + 63) / 64, 256, 0, stream>>>(agg, (const uint16_t*)xb, w1l_sw, w1r_sw, b1_n, h);
    // layer 2: t = h@W2l, u = h@W2r + b2 ; out = A·t + u
    gemm_dualB_cs<256, 128><<<(NN + 63) / 64, 256, 0, stream>>>(h, w2l_sw, w2r_sw, b2_n, t, u);
    agg_final_128<<<NN / 4, 256, 0, stream>>>((const uint32_t*)t, row_start, deg, csr, inv_deg,
                                              (const float2*)u, (float2*)d_out);
}

// Round 9
// 322.976 us; speedup vs baseline: 1.4558x; 1.0826x over previous
//
#include <hip/hip_runtime.h>
#include <hip/hip_bf16.h>
#include <stdint.h>

#define NN 50000
#define NE 800000
#define NB 196            // dst buckets: dst>>8
#define BCAP 8192         // per-bucket staging capacity (mean 4082, uniform dst)
#define EPB 2048
#define NBLK ((NE + EPB - 1) / EPB)   // 391

typedef __attribute__((ext_vector_type(8))) __bf16 bf16x8;
typedef __attribute__((ext_vector_type(4))) float f32x4;

__device__ __forceinline__ float bflo(uint32_t u) { return __uint_as_float(u << 16); }
__device__ __forceinline__ float bfhi(uint32_t u) { return __uint_as_float(u & 0xffff0000u); }
__device__ __forceinline__ uint16_t f2bf(float f) {
    uint32_t u = __float_as_uint(f);
    u += 0x7fffu + ((u >> 16) & 1u);   // RNE
    return (uint16_t)(u >> 16);
}
__device__ __forceinline__ float bf2f(uint16_t h) { return __uint_as_float(((uint32_t)h) << 16); }

// ---------------- detect dtypes + zero counters/deg ----------------
__global__ __launch_bounds__(256) void detect_zero(const uint32_t* __restrict__ xu,
                                                   const int* __restrict__ ei,
                                                   int* __restrict__ flags,
                                                   int* __restrict__ deg,
                                                   int* __restrict__ bucket_fill,
                                                   int* __restrict__ counter) {
    int gid = blockIdx.x * 256 + threadIdx.x;
    for (int i = gid; i < NN; i += gridDim.x * 256) deg[i] = 0;
    if (gid < NB) bucket_fill[gid] = 0;
    if (gid == 0) counter[0] = 0;
    if (blockIdx.x == 0) {
        __shared__ int cnt_f, cnt_i;
        if (threadIdx.x == 0) { cnt_f = 0; cnt_i = 0; }
        __syncthreads();
        uint32_t u = xu[threadIdx.x];
        uint32_t lo = u & 0xffffu;
        uint32_t e = (lo >> 7) & 0xffu;
        int ok = (lo == 0u) || (e >= 96u && e <= 150u);
        atomicAdd(&cnt_f, ok);
        if (threadIdx.x < 64) {
            int w = ei[2 * threadIdx.x + 1];
            atomicAdd(&cnt_i, (w != 0) ? 1 : 0);
        }
        __syncthreads();
        if (threadIdx.x == 0) {
            flags[0] = (cnt_f < 192) ? 1 : 0;
            flags[1] = (cnt_i < 4) ? 1 : 0;
        }
    }
}

// ---------------- fused: edge normalize + deg count + bucket-binned staging ----------------
__global__ __launch_bounds__(256) void norm_fill(const int* __restrict__ ei, const int* __restrict__ flags,
                                                 int* __restrict__ deg, int* __restrict__ bucket_fill,
                                                 uint2* __restrict__ staging) {
    __shared__ int hist[NB];
    __shared__ int curs[NB];
    __shared__ uint2 stash[EPB];
    for (int t = threadIdx.x; t < NB; t += 256) hist[t] = 0;
    __syncthreads();
    int base = blockIdx.x * EPB;
    int fl = flags[1];
    for (int i = 0; i < EPB; i += 256) {
        int e = base + i + threadIdx.x;
        uint2 v; v.x = 0u; v.y = 0xffffffffu;
        if (e < NE) {
            int s, d;
            if (fl) { s = ei[2 * e]; d = ei[2 * NE + 2 * e]; }
            else    { s = ei[e];     d = ei[NE + e]; }
            v.x = (unsigned)s; v.y = (unsigned)d;
            atomicAdd(&hist[d >> 8], 1);
            atomicAdd(&deg[d], 1);
        }
        stash[i + threadIdx.x] = v;
    }
    __syncthreads();
    for (int t = threadIdx.x; t < NB; t += 256) {
        int c = hist[t];
        curs[t] = c ? atomicAdd(&bucket_fill[t], c) : 0;
    }
    __syncthreads();
    for (int i = threadIdx.x; i < EPB; i += 256) {
        uint2 v = stash[i];
        if (v.y != 0xffffffffu) {
            int b = (int)(v.y >> 8);
            int p = atomicAdd(&curs[b], 1);
            if (p < BCAP) staging[((size_t)b << 13) + p] = v;
        }
    }
}

// ---------------- CSR fill, one block per bucket (L2-local scatter) ----------------
__global__ __launch_bounds__(256) void fill_csr_binned(const uint2* __restrict__ staging,
                                                       const int* __restrict__ bucket_fill,
                                                       int* __restrict__ cursor, int* __restrict__ csr) {
    int b = blockIdx.x;
    int cnt = bucket_fill[b];
    if (cnt > BCAP) cnt = BCAP;
    const uint2* seg = staging + ((size_t)b << 13);
    for (int e = threadIdx.x; e < cnt; e += 256) {
        uint2 v = seg[e];
        int pos = atomicAdd(&cursor[v.y], 1);
        csr[pos] = (int)v.x;
    }
}

__global__ __launch_bounds__(256) void norm_x(const void* __restrict__ x, const int* __restrict__ flags,
                                              uint32_t* __restrict__ out) {
    int i = blockIdx.x * 256 + threadIdx.x;  // < NN*64
    if (flags[0]) {
        float2 v = ((const float2*)x)[i];
        out[i] = (uint32_t)f2bf(v.x) | ((uint32_t)f2bf(v.y) << 16);
    } else {
        out[i] = ((const uint32_t*)x)[i];
    }
}

// ---------------- weights: normalize + swizzle into B-fragment layout, one pass ----------------
// frag id: [0,64) w1l | [64,128) w1r | [128,192) w2l | [192,256) w2r; then 384 bias elems
__global__ __launch_bounds__(256) void norm_weights_sw(const void* __restrict__ w1l, const void* __restrict__ b1,
                                                       const void* __restrict__ w1r, const void* __restrict__ w2l,
                                                       const void* __restrict__ b2, const void* __restrict__ w2r,
                                                       const int* __restrict__ flags,
                                                       uint16_t* __restrict__ w1l_sw, uint16_t* __restrict__ w1r_sw,
                                                       uint16_t* __restrict__ w2l_sw, uint16_t* __restrict__ w2r_sw,
                                                       uint16_t* __restrict__ bias_buf) {
    int tid = blockIdx.x * 256 + threadIdx.x;
    int fp32 = flags[0];
    if (tid < 16384) {
        int frag = tid >> 6, lane = tid & 63;
        const void* srcw; uint16_t* dst; int N; int fl;
        if (frag < 64)       { srcw = w1l; dst = w1l_sw; N = 256; fl = frag; }
        else if (frag < 128) { srcw = w1r; dst = w1r_sw; N = 256; fl = frag - 64; }
        else if (frag < 192) { srcw = w2l; dst = w2l_sw; N = 128; fl = frag - 128; }
        else                 { srcw = w2r; dst = w2r_sw; N = 128; fl = frag - 192; }
        int NTm = N >> 4;
        int kt = fl / NTm, nt = fl - kt * NTm;
        int k0 = kt * 32 + (lane >> 4) * 8, n = nt * 16 + (lane & 15);
        uint16_t* d = dst + (size_t)fl * 512 + lane * 8;
#pragma unroll
        for (int j = 0; j < 8; j++) {
            int si = (k0 + j) * N + n;
            d[j] = fp32 ? f2bf(((const float*)srcw)[si]) : ((const uint16_t*)srcw)[si];
        }
    } else if (tid < 16384 + 384) {
        int j = tid - 16384;
        const void* s = (j < 256) ? b1 : b2;
        int jj = (j < 256) ? j : j - 256;
        bias_buf[j] = fp32 ? f2bf(((const float*)s)[jj]) : ((const uint16_t*)s)[jj];
    }
}

// ---------------- CSR segment allocation (order-free) ----------------
__global__ __launch_bounds__(256) void alloc_rows(const int* __restrict__ deg, int* __restrict__ counter,
                                                  int* __restrict__ row_start, int* __restrict__ cursor,
                                                  float* __restrict__ inv_deg) {
    int node = blockIdx.x * 256 + threadIdx.x;
    int lane = threadIdx.x & 63;
    int d = (node < NN) ? deg[node] : 0;
    int incl = d;
#pragma unroll
    for (int o = 1; o < 64; o <<= 1) {
        int t = __shfl_up(incl, o, 64);
        if (lane >= o) incl += t;
    }
    int excl = incl - d;
    int wave_total = __shfl(incl, 63, 64);
    int base = 0;
    if (lane == 63) base = atomicAdd(counter, wave_total);
    base = __shfl(base, 63, 64);
    if (node < NN) {
        int rs = base + excl;
        row_start[node] = rs;
        cursor[node] = rs;
        inv_deg[node] = 1.0f / (float)(d > 0 ? d : 1);
    }
}

// ---------------- mean aggregation (unroll 8) ----------------
__global__ __launch_bounds__(256) void agg_mean_128(const uint32_t* __restrict__ xu,
                                                    const int* __restrict__ row_start,
                                                    const int* __restrict__ deg,
                                                    const int* __restrict__ csr,
                                                    const float* __restrict__ inv_deg,
                                                    uint32_t* __restrict__ outu) {
    int node = blockIdx.x * 4 + (threadIdx.x >> 6);
    int lane = threadIdx.x & 63;
    int beg = row_start[node], end = beg + deg[node];
    float lo[8], hi[8];
#pragma unroll
    for (int k = 0; k < 8; k++) { lo[k] = 0.f; hi[k] = 0.f; }
    int j = beg;
    for (; j + 8 <= end; j += 8) {
        int idx[8];
#pragma unroll
        for (int k = 0; k < 8; k++) idx[k] = csr[j + k];
#pragma unroll
        for (int k = 0; k < 8; k++) {
            uint32_t u = xu[(size_t)idx[k] * 64 + lane];
            lo[k] += bflo(u); hi[k] += bfhi(u);
        }
    }
    for (; j < end; j++) {
        uint32_t u = xu[(size_t)csr[j] * 64 + lane];
        lo[0] += bflo(u); hi[0] += bfhi(u);
    }
    float sc = inv_deg[node];
    float r0 = (((lo[0] + lo[1]) + (lo[2] + lo[3])) + ((lo[4] + lo[5]) + (lo[6] + lo[7]))) * sc;
    float r1 = (((hi[0] + hi[1]) + (hi[2] + hi[3])) + ((hi[4] + hi[5]) + (hi[6] + hi[7]))) * sc;
    outu[(size_t)node * 64 + lane] = (uint32_t)f2bf(r0) | ((uint32_t)f2bf(r1) << 16);
}

// final: out = mean_gather(t) + u, fp32 out (unroll 8)
__global__ __launch_bounds__(256) void agg_final_128(const uint32_t* __restrict__ tu,
                                                     const int* __restrict__ row_start,
                                                     const int* __restrict__ deg,
                                                     const int* __restrict__ csr,
                                                     const float* __restrict__ inv_deg,
                                                     const float2* __restrict__ u,
                                                     float2* __restrict__ out) {
    int node = blockIdx.x * 4 + (threadIdx.x >> 6);
    int lane = threadIdx.x & 63;
    int beg = row_start[node], end = beg + deg[node];
    float lo[8], hi[8];
#pragma unroll
    for (int k = 0; k < 8; k++) { lo[k] = 0.f; hi[k] = 0.f; }
    int j = beg;
    for (; j + 8 <= end; j += 8) {
        int idx[8];
#pragma unroll
        for (int k = 0; k < 8; k++) idx[k] = csr[j + k];
#pragma unroll
        for (int k = 0; k < 8; k++) {
            uint32_t v = tu[(size_t)idx[k] * 64 + lane];
            lo[k] += bflo(v); hi[k] += bfhi(v);
        }
    }
    for (; j < end; j++) {
        uint32_t v = tu[(size_t)csr[j] * 64 + lane];
        lo[0] += bflo(v); hi[0] += bfhi(v);
    }
    float sc = inv_deg[node];
    float2 uv = u[(size_t)node * 64 + lane];
    float2 r;
    r.x = (((lo[0] + lo[1]) + (lo[2] + lo[3])) + ((lo[4] + lo[5]) + (lo[6] + lo[7]))) * sc + uv.x;
    r.y = (((hi[0] + hi[1]) + (hi[2] + hi[3])) + ((hi[4] + hi[5]) + (hi[6] + hi[7]))) * sc + uv.y;
    out[(size_t)node * 64 + lane] = r;
}

// ---------------- layer-1 GEMM: B-fragments preloaded in registers ----------------
template <int K, int N>
__global__ __launch_bounds__(256) void gemm_dualA_breg(const uint16_t* __restrict__ A1,
                                                       const uint16_t* __restrict__ A2,
                                                       const uint16_t* __restrict__ W1sw,
                                                       const uint16_t* __restrict__ W2sw,
                                                       const uint16_t* __restrict__ bias,
                                                       uint16_t* __restrict__ C) {
    constexpr int NTF = N / 16, NTW = NTF / 4, KT = K / 32;
    int wave = threadIdx.x >> 6, lane = threadIdx.x & 63;
    int row0 = blockIdx.x * 64, bt = wave * NTW;
    int m = lane & 15, q = lane >> 4;
    int ar[4];
#pragma unroll
    for (int rf = 0; rf < 4; rf++) { int r = row0 + rf * 16 + m; ar[rf] = (r < NN) ? r : (NN - 1); }

    bf16x8 B1[KT][NTW], B2[KT][NTW];
#pragma unroll
    for (int kt = 0; kt < KT; kt++)
#pragma unroll
        for (int nt = 0; nt < NTW; nt++) {
            B1[kt][nt] = *(const bf16x8*)(W1sw + ((size_t)(kt * NTF + bt + nt)) * 512 + lane * 8);
            B2[kt][nt] = *(const bf16x8*)(W2sw + ((size_t)(kt * NTF + bt + nt)) * 512 + lane * 8);
        }

    f32x4 acc[4][NTW];
#pragma unroll
    for (int rf = 0; rf < 4; rf++)
#pragma unroll
        for (int nt = 0; nt < NTW; nt++)
#pragma unroll
            for (int i = 0; i < 4; i++) acc[rf][nt][i] = 0.f;

#pragma unroll
    for (int kt = 0; kt < KT; kt++) {
        bf16x8 a0 = *(const bf16x8*)(A1 + (size_t)ar[0] * K + kt * 32 + q * 8);
        bf16x8 a1 = *(const bf16x8*)(A1 + (size_t)ar[1] * K + kt * 32 + q * 8);
        bf16x8 a2 = *(const bf16x8*)(A1 + (size_t)ar[2] * K + kt * 32 + q * 8);
        bf16x8 a3 = *(const bf16x8*)(A1 + (size_t)ar[3] * K + kt * 32 + q * 8);
#pragma unroll
        for (int nt = 0; nt < NTW; nt++) {
            acc[0][nt] = __builtin_amdgcn_mfma_f32_16x16x32_bf16(a0, B1[kt][nt], acc[0][nt], 0, 0, 0);
            acc[1][nt] = __builtin_amdgcn_mfma_f32_16x16x32_bf16(a1, B1[kt][nt], acc[1][nt], 0, 0, 0);
            acc[2][nt] = __builtin_amdgcn_mfma_f32_16x16x32_bf16(a2, B1[kt][nt], acc[2][nt], 0, 0, 0);
            acc[3][nt] = __builtin_amdgcn_mfma_f32_16x16x32_bf16(a3, B1[kt][nt], acc[3][nt], 0, 0, 0);
        }
    }
#pragma unroll
    for (int kt = 0; kt < KT; kt++) {
        bf16x8 a0 = *(const bf16x8*)(A2 + (size_t)ar[0] * K + kt * 32 + q * 8);
        bf16x8 a1 = *(const bf16x8*)(A2 + (size_t)ar[1] * K + kt * 32 + q * 8);
        bf16x8 a2 = *(const bf16x8*)(A2 + (size_t)ar[2] * K + kt * 32 + q * 8);
        bf16x8 a3 = *(const bf16x8*)(A2 + (size_t)ar[3] * K + kt * 32 + q * 8);
#pragma unroll
        for (int nt = 0; nt < NTW; nt++) {
            acc[0][nt] = __builtin_amdgcn_mfma_f32_16x16x32_bf16(a0, B2[kt][nt], acc[0][nt], 0, 0, 0);
            acc[1][nt] = __builtin_amdgcn_mfma_f32_16x16x32_bf16(a1, B2[kt][nt], acc[1][nt], 0, 0, 0);
            acc[2][nt] = __builtin_amdgcn_mfma_f32_16x16x32_bf16(a2, B2[kt][nt], acc[2][nt], 0, 0, 0);
            acc[3][nt] = __builtin_amdgcn_mfma_f32_16x16x32_bf16(a3, B2[kt][nt], acc[3][nt], 0, 0, 0);
        }
    }

#pragma unroll
    for (int nt = 0; nt < NTW; nt++) {
        int col = (bt + nt) * 16 + m;
        float bv = bf2f(bias[col]);
#pragma unroll
        for (int rf = 0; rf < 4; rf++)
#pragma unroll
            for (int i = 0; i < 4; i++) {
                int r = row0 + rf * 16 + q * 4 + i;
                if (r < NN) {
                    float v = fmaxf(acc[rf][nt][i] + bv, 0.f);
                    C[(size_t)r * N + col] = f2bf(v);
                }
            }
    }
}

// ---------------- layer-2 GEMM (dual-B): t = A@W1 (bf16), u = A@W2 + bias (fp32), B in regs ----------------
template <int K, int N>
__global__ __launch_bounds__(256) void gemm_dualB_breg(const uint16_t* __restrict__ A,
                                                       const uint16_t* __restrict__ W1sw,
                                                       const uint16_t* __restrict__ W2sw,
                                                       const uint16_t* __restrict__ bias,
                                                       uint16_t* __restrict__ T,
                                                       float* __restrict__ U) {
    constexpr int NTF = N / 16, NTW = NTF / 4, KT = K / 32;
    int wave = threadIdx.x >> 6, lane = threadIdx.x & 63;
    int row0 = blockIdx.x * 64, bt = wave * NTW;
    int m = lane & 15, q = lane >> 4;
    int ar[4];
#pragma unroll
    for (int rf = 0; rf < 4; rf++) { int r = row0 + rf * 16 + m; ar[rf] = (r < NN) ? r : (NN - 1); }

    bf16x8 B1[KT][NTW], B2[KT][NTW];
#pragma unroll
    for (int kt = 0; kt < KT; kt++)
#pragma unroll
        for (int nt = 0; nt < NTW; nt++) {
            B1[kt][nt] = *(const bf16x8*)(W1sw + ((size_t)(kt * NTF + bt + nt)) * 512 + lane * 8);
            B2[kt][nt] = *(const bf16x8*)(W2sw + ((size_t)(kt * NTF + bt + nt)) * 512 + lane * 8);
        }

    f32x4 acc1[4][NTW], acc2[4][NTW];
#pragma unroll
    for (int rf = 0; rf < 4; rf++)
#pragma unroll
        for (int nt = 0; nt < NTW; nt++)
#pragma unroll
            for (int i = 0; i < 4; i++) { acc1[rf][nt][i] = 0.f; acc2[rf][nt][i] = 0.f; }

#pragma unroll
    for (int kt = 0; kt < KT; kt++) {
        bf16x8 a0 = *(const bf16x8*)(A + (size_t)ar[0] * K + kt * 32 + q * 8);
        bf16x8 a1 = *(const bf16x8*)(A + (size_t)ar[1] * K + kt * 32 + q * 8);
        bf16x8 a2 = *(const bf16x8*)(A + (size_t)ar[2] * K + kt * 32 + q * 8);
        bf16x8 a3 = *(const bf16x8*)(A + (size_t)ar[3] * K + kt * 32 + q * 8);
#pragma unroll
        for (int nt = 0; nt < NTW; nt++) {
            acc1[0][nt] = __builtin_amdgcn_mfma_f32_16x16x32_bf16(a0, B1[kt][nt], acc1[0][nt], 0, 0, 0);
            acc1[1][nt] = __builtin_amdgcn_mfma_f32_16x16x32_bf16(a1, B1[kt][nt], acc1[1][nt], 0, 0, 0);
            acc1[2][nt] = __builtin_amdgcn_mfma_f32_16x16x32_bf16(a2, B1[kt][nt], acc1[2][nt], 0, 0, 0);
            acc1[3][nt] = __builtin_amdgcn_mfma_f32_16x16x32_bf16(a3, B1[kt][nt], acc1[3][nt], 0, 0, 0);
            acc2[0][nt] = __builtin_amdgcn_mfma_f32_16x16x32_bf16(a0, B2[kt][nt], acc2[0][nt], 0, 0, 0);
            acc2[1][nt] = __builtin_amdgcn_mfma_f32_16x16x32_bf16(a1, B2[kt][nt], acc2[1][nt], 0, 0, 0);
            acc2[2][nt] = __builtin_amdgcn_mfma_f32_16x16x32_bf16(a2, B2[kt][nt], acc2[2][nt], 0, 0, 0);
            acc2[3][nt] = __builtin_amdgcn_mfma_f32_16x16x32_bf16(a3, B2[kt][nt], acc2[3][nt], 0, 0, 0);
        }
    }

#pragma unroll
    for (int nt = 0; nt < NTW; nt++) {
        int col = (bt + nt) * 16 + m;
        float bv = bf2f(bias[col]);
#pragma unroll
        for (int rf = 0; rf < 4; rf++)
#pragma unroll
            for (int i = 0; i < 4; i++) {
                int r = row0 + rf * 16 + q * 4 + i;
                if (r < NN) {
                    T[(size_t)r * N + col] = f2bf(acc1[rf][nt][i]);
                    U[(size_t)r * N + col] = acc2[rf][nt][i] + bv;
                }
            }
    }
}

extern "C" void kernel_launch(void* const* d_in, const int* in_sizes, int n_in,
                              void* d_out, int out_size, void* d_ws, size_t ws_size,
                              hipStream_t stream) {
    const void* x_raw  = d_in[0];
    const int*  ei     = (const int*)d_in[1];
    const void* W1l    = d_in[2];
    const void* b1     = d_in[3];
    const void* W1r    = d_in[4];
    const void* W2l    = d_in[5];
    const void* b2     = d_in[6];
    const void* W2r    = d_in[7];

    uint8_t* ws = (uint8_t*)d_ws;
    size_t off = 0;
    auto alloc = [&](size_t b) -> void* {
        void* p = ws + off;
        off += (b + 255) & ~(size_t)255;
        return p;
    };
    int*      flags       = (int*)alloc(256);
    int*      counter     = (int*)alloc(256);
    int*      bucket_fill = (int*)alloc((NB + 4) * 4);
    int*      deg         = (int*)alloc((size_t)NN * 4);
    float*    inv_deg     = (float*)alloc((size_t)NN * 4);
    int*      row_start   = (int*)alloc((size_t)NN * 4);
    int*      cursor      = (int*)alloc((size_t)NN * 4);
    int*      csr         = (int*)alloc((size_t)NE * 4);
    uint32_t* xb          = (uint32_t*)alloc((size_t)NN * 64 * 4);
    uint16_t* bias_buf    = (uint16_t*)alloc(384 * 2);
    uint16_t* agg         = (uint16_t*)alloc((size_t)NN * 128 * 2);
    uint16_t* h           = (uint16_t*)alloc((size_t)NN * 256 * 2);
    uint16_t* t           = (uint16_t*)alloc((size_t)NN * 128 * 2);
    float*    u           = (float*)alloc((size_t)NN * 128 * 4);
    uint16_t* w1l_sw      = (uint16_t*)alloc(128 * 256 * 2);
    uint16_t* w1r_sw      = (uint16_t*)alloc(128 * 256 * 2);
    uint16_t* w2l_sw      = (uint16_t*)alloc(256 * 128 * 2);
    uint16_t* w2r_sw      = (uint16_t*)alloc(256 * 128 * 2);

    // staging aliases h: 196*8192*8B = 12.85 MB <= 25.6 MB; consumed before h is written
    uint2* staging = (uint2*)h;

    detect_zero<<<64, 256, 0, stream>>>((const uint32_t*)x_raw, ei, flags, deg, bucket_fill, counter);

    norm_fill<<<NBLK, 256, 0, stream>>>(ei, flags, deg, bucket_fill, staging);
    norm_x<<<(NN * 64 + 255) / 256, 256, 0, stream>>>(x_raw, flags, xb);
    norm_weights_sw<<<66, 256, 0, stream>>>(W1l, b1, W1r, W2l, b2, W2r, flags,
                                            w1l_sw, w1r_sw, w2l_sw, w2r_sw, bias_buf);

    alloc_rows<<<(NN + 255) / 256, 256, 0, stream>>>(deg, counter, row_start, cursor, inv_deg);
    fill_csr_binned<<<NB, 256, 0, stream>>>(staging, bucket_fill, cursor, csr);

    // layer 1: agg = A·x ; h = relu(agg@W1l + x@W1r + b1)
    agg_mean_128<<<NN / 4, 256, 0, stream>>>(xb, row_start, deg, csr, inv_deg, (uint32_t*)agg);
    gemm_dualA_breg<128, 256><<<(NN + 63) / 64, 256, 0, stream>>>(agg, (const uint16_t*)xb,
                                                                  w1l_sw, w1r_sw, bias_buf, h);
    // layer 2: t = h@W2l, u = h@W2r + b2 ; out = A·t + u
    gemm_dualB_breg<256, 128><<<(NN + 63) / 64, 256, 0, stream>>>(h, w2l_sw, w2r_sw, bias_buf + 256, t, u);
    agg_final_128<<<NN / 4, 256, 0, stream>>>((const uint32_t*)t, row_start, deg, csr, inv_deg,
                                              (const float2*)u, (float2*)d_out);
}

// Round 10
// 277.685 us; speedup vs baseline: 1.6932x; 1.1631x over previous
//
#include <hip/hip_runtime.h>
#include <hip/hip_bf16.h>
#include <stdint.h>

#define NN 50000
#define NE 800000
#define NB 196            // dst buckets: dst>>8 (256 nodes each)
#define EPB 2048
#define NBLK ((NE + EPB - 1) / EPB)   // 391

typedef __attribute__((ext_vector_type(8))) __bf16 bf16x8;
typedef __attribute__((ext_vector_type(4))) float f32x4;

__device__ __forceinline__ float bflo(uint32_t u) { return __uint_as_float(u << 16); }
__device__ __forceinline__ float bfhi(uint32_t u) { return __uint_as_float(u & 0xffff0000u); }
__device__ __forceinline__ uint16_t f2bf(float f) {
    uint32_t u = __float_as_uint(f);
    u += 0x7fffu + ((u >> 16) & 1u);   // RNE
    return (uint16_t)(u >> 16);
}
__device__ __forceinline__ float bf2f(uint16_t h) { return __uint_as_float(((uint32_t)h) << 16); }

// ---------------- dtype detection ----------------
__global__ __launch_bounds__(256) void detect(const uint32_t* __restrict__ xu,
                                              const int* __restrict__ ei,
                                              int* __restrict__ flags) {
    __shared__ int cnt_f, cnt_i;
    if (threadIdx.x == 0) { cnt_f = 0; cnt_i = 0; }
    __syncthreads();
    uint32_t u = xu[threadIdx.x];
    uint32_t lo = u & 0xffffu;
    uint32_t e = (lo >> 7) & 0xffu;
    int ok = (lo == 0u) || (e >= 96u && e <= 150u);
    atomicAdd(&cnt_f, ok);
    if (threadIdx.x < 64) {
        int w = ei[2 * threadIdx.x + 1];
        atomicAdd(&cnt_i, (w != 0) ? 1 : 0);
    }
    __syncthreads();
    if (threadIdx.x == 0) {
        flags[0] = (cnt_f < 192) ? 1 : 0;
        flags[1] = (cnt_i < 4) ? 1 : 0;
    }
}

// ---------------- pass 1: per-block bucket histograms (LDS atomics only) ----------------
__global__ __launch_bounds__(256) void hist_pass(const int* __restrict__ ei, const int* __restrict__ flags,
                                                 int* __restrict__ histM) {
    __shared__ int hist[NB];
    for (int i = threadIdx.x; i < NB; i += 256) hist[i] = 0;
    __syncthreads();
    int base = blockIdx.x * EPB;
    int fl = flags[1];
    for (int i = 0; i < EPB; i += 256) {
        int e = base + i + threadIdx.x;
        if (e < NE) {
            int d = fl ? ei[2 * NE + 2 * e] : ei[NE + e];
            atomicAdd(&hist[d >> 8], 1);
        }
    }
    __syncthreads();
    for (int i = threadIdx.x; i < NB; i += 256) histM[i * NBLK + blockIdx.x] = hist[i];
}

// ---------------- pass 2a: per-bucket scan over block counts ----------------
__global__ __launch_bounds__(512) void scan_rows(int* __restrict__ histM, int* __restrict__ bucket_tot) {
    __shared__ int sm[512];
    int b = blockIdx.x, t = threadIdx.x;
    int v = (t < NBLK) ? histM[b * NBLK + t] : 0;
    sm[t] = v;
    __syncthreads();
    for (int o = 1; o < 512; o <<= 1) {
        int x = (t >= o) ? sm[t - o] : 0;
        __syncthreads();
        sm[t] += x;
        __syncthreads();
    }
    if (t < NBLK) histM[b * NBLK + t] = sm[t] - v;   // exclusive prefix in-place
    if (t == 511) bucket_tot[b] = sm[511];
}

// ---------------- pass 2b: scan bucket totals -> bucket bases ----------------
__global__ __launch_bounds__(256) void scan_tot(const int* __restrict__ bucket_tot, int* __restrict__ bucket_base) {
    __shared__ int sm[256];
    int t = threadIdx.x;
    int v = (t < NB) ? bucket_tot[t] : 0;
    sm[t] = v;
    __syncthreads();
    for (int o = 1; o < 256; o <<= 1) {
        int x = (t >= o) ? sm[t - o] : 0;
        __syncthreads();
        sm[t] += x;
        __syncthreads();
    }
    if (t < NB) bucket_base[t] = sm[t] - v;
    if (t == 0) bucket_base[NB] = NE;
}

// ---------------- pass 3: scatter edges into reserved bucket runs (no global atomics) ----------------
// staging entry: (dst&0xff)<<16 | src   (NN < 2^16)
__global__ __launch_bounds__(256) void scatter_pass(const int* __restrict__ ei, const int* __restrict__ flags,
                                                    const int* __restrict__ histM, const int* __restrict__ bucket_base,
                                                    uint32_t* __restrict__ staging) {
    __shared__ int curs[NB];
    int blk = blockIdx.x, t = threadIdx.x;
    for (int i = t; i < NB; i += 256) curs[i] = bucket_base[i] + histM[i * NBLK + blk];
    __syncthreads();
    int base = blk * EPB;
    int fl = flags[1];
    for (int i = 0; i < EPB; i += 256) {
        int e = base + i + t;
        if (e < NE) {
            int s, d;
            if (fl) { s = ei[2 * e]; d = ei[2 * NE + 2 * e]; }
            else    { s = ei[e];     d = ei[NE + e]; }
            int p = atomicAdd(&curs[d >> 8], 1);
            staging[p] = ((uint32_t)(d & 0xff) << 16) | (uint32_t)s;
        }
    }
}

// ---------------- pass 4: per-bucket CSR build, all bookkeeping in LDS ----------------
__global__ __launch_bounds__(256) void build_csr(const uint32_t* __restrict__ staging,
                                                 const int* __restrict__ bucket_base,
                                                 int* __restrict__ row_start, int* __restrict__ deg,
                                                 float* __restrict__ inv_deg, int* __restrict__ csr) {
    __shared__ int degs[256];
    __shared__ int sm[256];
    __shared__ int curs[256];
    int b = blockIdx.x, t = threadIdx.x;
    int beg = bucket_base[b], cnt = bucket_base[b + 1] - beg;
    degs[t] = 0;
    __syncthreads();
    for (int i = t; i < cnt; i += 256) atomicAdd(&degs[(staging[beg + i] >> 16) & 0xff], 1);
    __syncthreads();
    int d = degs[t];
    sm[t] = d;
    __syncthreads();
    for (int o = 1; o < 256; o <<= 1) {
        int x = (t >= o) ? sm[t - o] : 0;
        __syncthreads();
        sm[t] += x;
        __syncthreads();
    }
    int excl = sm[t] - d;
    curs[t] = excl;
    int node = b * 256 + t;
    if (node < NN) {
        row_start[node] = beg + excl;
        deg[node] = d;
        inv_deg[node] = 1.0f / (float)(d > 0 ? d : 1);
    }
    __syncthreads();
    for (int i = t; i < cnt; i += 256) {
        uint32_t u = staging[beg + i];
        int dl = (u >> 16) & 0xff;
        int p = atomicAdd(&curs[dl], 1);
        csr[beg + p] = (int)(u & 0xffffu);
    }
}

__global__ __launch_bounds__(256) void norm_x(const void* __restrict__ x, const int* __restrict__ flags,
                                              uint32_t* __restrict__ out) {
    int i = blockIdx.x * 256 + threadIdx.x;  // < NN*64
    if (flags[0]) {
        float2 v = ((const float2*)x)[i];
        out[i] = (uint32_t)f2bf(v.x) | ((uint32_t)f2bf(v.y) << 16);
    } else {
        out[i] = ((const uint32_t*)x)[i];
    }
}

// ---------------- weights: normalize + swizzle into B-fragment layout ----------------
__global__ __launch_bounds__(256) void norm_weights_sw(const void* __restrict__ w1l, const void* __restrict__ b1,
                                                       const void* __restrict__ w1r, const void* __restrict__ w2l,
                                                       const void* __restrict__ b2, const void* __restrict__ w2r,
                                                       const int* __restrict__ flags,
                                                       uint16_t* __restrict__ w1l_sw, uint16_t* __restrict__ w1r_sw,
                                                       uint16_t* __restrict__ w2l_sw, uint16_t* __restrict__ w2r_sw,
                                                       uint16_t* __restrict__ bias_buf) {
    int tid = blockIdx.x * 256 + threadIdx.x;
    int fp32 = flags[0];
    if (tid < 16384) {
        int frag = tid >> 6, lane = tid & 63;
        const void* srcw; uint16_t* dst; int N; int fl;
        if (frag < 64)       { srcw = w1l; dst = w1l_sw; N = 256; fl = frag; }
        else if (frag < 128) { srcw = w1r; dst = w1r_sw; N = 256; fl = frag - 64; }
        else if (frag < 192) { srcw = w2l; dst = w2l_sw; N = 128; fl = frag - 128; }
        else                 { srcw = w2r; dst = w2r_sw; N = 128; fl = frag - 192; }
        int NTm = N >> 4;
        int kt = fl / NTm, nt = fl - kt * NTm;
        int k0 = kt * 32 + (lane >> 4) * 8, n = nt * 16 + (lane & 15);
        uint16_t* d = dst + (size_t)fl * 512 + lane * 8;
#pragma unroll
        for (int j = 0; j < 8; j++) {
            int si = (k0 + j) * N + n;
            d[j] = fp32 ? f2bf(((const float*)srcw)[si]) : ((const uint16_t*)srcw)[si];
        }
    } else if (tid < 16384 + 384) {
        int j = tid - 16384;
        const void* s = (j < 256) ? b1 : b2;
        int jj = (j < 256) ? j : j - 256;
        bias_buf[j] = fp32 ? f2bf(((const float*)s)[jj]) : ((const uint16_t*)s)[jj];
    }
}

// ---------------- mean aggregation (unroll 8) ----------------
__global__ __launch_bounds__(256) void agg_mean_128(const uint32_t* __restrict__ xu,
                                                    const int* __restrict__ row_start,
                                                    const int* __restrict__ deg,
                                                    const int* __restrict__ csr,
                                                    const float* __restrict__ inv_deg,
                                                    uint32_t* __restrict__ outu) {
    int node = blockIdx.x * 4 + (threadIdx.x >> 6);
    int lane = threadIdx.x & 63;
    int beg = row_start[node], end = beg + deg[node];
    float lo[8], hi[8];
#pragma unroll
    for (int k = 0; k < 8; k++) { lo[k] = 0.f; hi[k] = 0.f; }
    int j = beg;
    for (; j + 8 <= end; j += 8) {
        int idx[8];
#pragma unroll
        for (int k = 0; k < 8; k++) idx[k] = csr[j + k];
#pragma unroll
        for (int k = 0; k < 8; k++) {
            uint32_t u = xu[(size_t)idx[k] * 64 + lane];
            lo[k] += bflo(u); hi[k] += bfhi(u);
        }
    }
    for (; j < end; j++) {
        uint32_t u = xu[(size_t)csr[j] * 64 + lane];
        lo[0] += bflo(u); hi[0] += bfhi(u);
    }
    float sc = inv_deg[node];
    float r0 = (((lo[0] + lo[1]) + (lo[2] + lo[3])) + ((lo[4] + lo[5]) + (lo[6] + lo[7]))) * sc;
    float r1 = (((hi[0] + hi[1]) + (hi[2] + hi[3])) + ((hi[4] + hi[5]) + (hi[6] + hi[7]))) * sc;
    outu[(size_t)node * 64 + lane] = (uint32_t)f2bf(r0) | ((uint32_t)f2bf(r1) << 16);
}

// final: out = mean_gather(t) + u, fp32 out (unroll 8)
__global__ __launch_bounds__(256) void agg_final_128(const uint32_t* __restrict__ tu,
                                                     const int* __restrict__ row_start,
                                                     const int* __restrict__ deg,
                                                     const int* __restrict__ csr,
                                                     const float* __restrict__ inv_deg,
                                                     const float2* __restrict__ u,
                                                     float2* __restrict__ out) {
    int node = blockIdx.x * 4 + (threadIdx.x >> 6);
    int lane = threadIdx.x & 63;
    int beg = row_start[node], end = beg + deg[node];
    float lo[8], hi[8];
#pragma unroll
    for (int k = 0; k < 8; k++) { lo[k] = 0.f; hi[k] = 0.f; }
    int j = beg;
    for (; j + 8 <= end; j += 8) {
        int idx[8];
#pragma unroll
        for (int k = 0; k < 8; k++) idx[k] = csr[j + k];
#pragma unroll
        for (int k = 0; k < 8; k++) {
            uint32_t v = tu[(size_t)idx[k] * 64 + lane];
            lo[k] += bflo(v); hi[k] += bfhi(v);
        }
    }
    for (; j < end; j++) {
        uint32_t v = tu[(size_t)csr[j] * 64 + lane];
        lo[0] += bflo(v); hi[0] += bfhi(v);
    }
    float sc = inv_deg[node];
    float2 uv = u[(size_t)node * 64 + lane];
    float2 r;
    r.x = (((lo[0] + lo[1]) + (lo[2] + lo[3])) + ((lo[4] + lo[5]) + (lo[6] + lo[7]))) * sc + uv.x;
    r.y = (((hi[0] + hi[1]) + (hi[2] + hi[3])) + ((hi[4] + hi[5]) + (hi[6] + hi[7]))) * sc + uv.y;
    out[(size_t)node * 64 + lane] = r;
}

// ---------------- layer-1 GEMM: B-fragments preloaded in registers ----------------
template <int K, int N>
__global__ __launch_bounds__(256) void gemm_dualA_breg(const uint16_t* __restrict__ A1,
                                                       const uint16_t* __restrict__ A2,
                                                       const uint16_t* __restrict__ W1sw,
                                                       const uint16_t* __restrict__ W2sw,
                                                       const uint16_t* __restrict__ bias,
                                                       uint16_t* __restrict__ C) {
    constexpr int NTF = N / 16, NTW = NTF / 4, KT = K / 32;
    int wave = threadIdx.x >> 6, lane = threadIdx.x & 63;
    int row0 = blockIdx.x * 64, bt = wave * NTW;
    int m = lane & 15, q = lane >> 4;
    int ar[4];
#pragma unroll
    for (int rf = 0; rf < 4; rf++) { int r = row0 + rf * 16 + m; ar[rf] = (r < NN) ? r : (NN - 1); }

    bf16x8 B1[KT][NTW], B2[KT][NTW];
#pragma unroll
    for (int kt = 0; kt < KT; kt++)
#pragma unroll
        for (int nt = 0; nt < NTW; nt++) {
            B1[kt][nt] = *(const bf16x8*)(W1sw + ((size_t)(kt * NTF + bt + nt)) * 512 + lane * 8);
            B2[kt][nt] = *(const bf16x8*)(W2sw + ((size_t)(kt * NTF + bt + nt)) * 512 + lane * 8);
        }

    f32x4 acc[4][NTW];
#pragma unroll
    for (int rf = 0; rf < 4; rf++)
#pragma unroll
        for (int nt = 0; nt < NTW; nt++)
#pragma unroll
            for (int i = 0; i < 4; i++) acc[rf][nt][i] = 0.f;

#pragma unroll
    for (int kt = 0; kt < KT; kt++) {
        bf16x8 a0 = *(const bf16x8*)(A1 + (size_t)ar[0] * K + kt * 32 + q * 8);
        bf16x8 a1 = *(const bf16x8*)(A1 + (size_t)ar[1] * K + kt * 32 + q * 8);
        bf16x8 a2 = *(const bf16x8*)(A1 + (size_t)ar[2] * K + kt * 32 + q * 8);
        bf16x8 a3 = *(const bf16x8*)(A1 + (size_t)ar[3] * K + kt * 32 + q * 8);
#pragma unroll
        for (int nt = 0; nt < NTW; nt++) {
            acc[0][nt] = __builtin_amdgcn_mfma_f32_16x16x32_bf16(a0, B1[kt][nt], acc[0][nt], 0, 0, 0);
            acc[1][nt] = __builtin_amdgcn_mfma_f32_16x16x32_bf16(a1, B1[kt][nt], acc[1][nt], 0, 0, 0);
            acc[2][nt] = __builtin_amdgcn_mfma_f32_16x16x32_bf16(a2, B1[kt][nt], acc[2][nt], 0, 0, 0);
            acc[3][nt] = __builtin_amdgcn_mfma_f32_16x16x32_bf16(a3, B1[kt][nt], acc[3][nt], 0, 0, 0);
        }
    }
#pragma unroll
    for (int kt = 0; kt < KT; kt++) {
        bf16x8 a0 = *(const bf16x8*)(A2 + (size_t)ar[0] * K + kt * 32 + q * 8);
        bf16x8 a1 = *(const bf16x8*)(A2 + (size_t)ar[1] * K + kt * 32 + q * 8);
        bf16x8 a2 = *(const bf16x8*)(A2 + (size_t)ar[2] * K + kt * 32 + q * 8);
        bf16x8 a3 = *(const bf16x8*)(A2 + (size_t)ar[3] * K + kt * 32 + q * 8);
#pragma unroll
        for (int nt = 0; nt < NTW; nt++) {
            acc[0][nt] = __builtin_amdgcn_mfma_f32_16x16x32_bf16(a0, B2[kt][nt], acc[0][nt], 0, 0, 0);
            acc[1][nt] = __builtin_amdgcn_mfma_f32_16x16x32_bf16(a1, B2[kt][nt], acc[1][nt], 0, 0, 0);
            acc[2][nt] = __builtin_amdgcn_mfma_f32_16x16x32_bf16(a2, B2[kt][nt], acc[2][nt], 0, 0, 0);
            acc[3][nt] = __builtin_amdgcn_mfma_f32_16x16x32_bf16(a3, B2[kt][nt], acc[3][nt], 0, 0, 0);
        }
    }

#pragma unroll
    for (int nt = 0; nt < NTW; nt++) {
        int col = (bt + nt) * 16 + m;
        float bv = bf2f(bias[col]);
#pragma unroll
        for (int rf = 0; rf < 4; rf++)
#pragma unroll
            for (int i = 0; i < 4; i++) {
                int r = row0 + rf * 16 + q * 4 + i;
                if (r < NN) {
                    float v = fmaxf(acc[rf][nt][i] + bv, 0.f);
                    C[(size_t)r * N + col] = f2bf(v);
                }
            }
    }
}

// ---------------- layer-2 GEMM (dual-B): t = A@W1 (bf16), u = A@W2 + bias (fp32) ----------------
template <int K, int N>
__global__ __launch_bounds__(256) void gemm_dualB_breg(const uint16_t* __restrict__ A,
                                                       const uint16_t* __restrict__ W1sw,
                                                       const uint16_t* __restrict__ W2sw,
                                                       const uint16_t* __restrict__ bias,
                                                       uint16_t* __restrict__ T,
                                                       float* __restrict__ U) {
    constexpr int NTF = N / 16, NTW = NTF / 4, KT = K / 32;
    int wave = threadIdx.x >> 6, lane = threadIdx.x & 63;
    int row0 = blockIdx.x * 64, bt = wave * NTW;
    int m = lane & 15, q = lane >> 4;
    int ar[4];
#pragma unroll
    for (int rf = 0; rf < 4; rf++) { int r = row0 + rf * 16 + m; ar[rf] = (r < NN) ? r : (NN - 1); }

    bf16x8 B1[KT][NTW], B2[KT][NTW];
#pragma unroll
    for (int kt = 0; kt < KT; kt++)
#pragma unroll
        for (int nt = 0; nt < NTW; nt++) {
            B1[kt][nt] = *(const bf16x8*)(W1sw + ((size_t)(kt * NTF + bt + nt)) * 512 + lane * 8);
            B2[kt][nt] = *(const bf16x8*)(W2sw + ((size_t)(kt * NTF + bt + nt)) * 512 + lane * 8);
        }

    f32x4 acc1[4][NTW], acc2[4][NTW];
#pragma unroll
    for (int rf = 0; rf < 4; rf++)
#pragma unroll
        for (int nt = 0; nt < NTW; nt++)
#pragma unroll
            for (int i = 0; i < 4; i++) { acc1[rf][nt][i] = 0.f; acc2[rf][nt][i] = 0.f; }

#pragma unroll
    for (int kt = 0; kt < KT; kt++) {
        bf16x8 a0 = *(const bf16x8*)(A + (size_t)ar[0] * K + kt * 32 + q * 8);
        bf16x8 a1 = *(const bf16x8*)(A + (size_t)ar[1] * K + kt * 32 + q * 8);
        bf16x8 a2 = *(const bf16x8*)(A + (size_t)ar[2] * K + kt * 32 + q * 8);
        bf16x8 a3 = *(const bf16x8*)(A + (size_t)ar[3] * K + kt * 32 + q * 8);
#pragma unroll
        for (int nt = 0; nt < NTW; nt++) {
            acc1[0][nt] = __builtin_amdgcn_mfma_f32_16x16x32_bf16(a0, B1[kt][nt], acc1[0][nt], 0, 0, 0);
            acc1[1][nt] = __builtin_amdgcn_mfma_f32_16x16x32_bf16(a1, B1[kt][nt], acc1[1][nt], 0, 0, 0);
            acc1[2][nt] = __builtin_amdgcn_mfma_f32_16x16x32_bf16(a2, B1[kt][nt], acc1[2][nt], 0, 0, 0);
            acc1[3][nt] = __builtin_amdgcn_mfma_f32_16x16x32_bf16(a3, B1[kt][nt], acc1[3][nt], 0, 0, 0);
            acc2[0][nt] = __builtin_amdgcn_mfma_f32_16x16x32_bf16(a0, B2[kt][nt], acc2[0][nt], 0, 0, 0);
            acc2[1][nt] = __builtin_amdgcn_mfma_f32_16x16x32_bf16(a1, B2[kt][nt], acc2[1][nt], 0, 0, 0);
            acc2[2][nt] = __builtin_amdgcn_mfma_f32_16x16x32_bf16(a2, B2[kt][nt], acc2[2][nt], 0, 0, 0);
            acc2[3][nt] = __builtin_amdgcn_mfma_f32_16x16x32_bf16(a3, B2[kt][nt], acc2[3][nt], 0, 0, 0);
        }
    }

#pragma unroll
    for (int nt = 0; nt < NTW; nt++) {
        int col = (bt + nt) * 16 + m;
        float bv = bf2f(bias[col]);
#pragma unroll
        for (int rf = 0; rf < 4; rf++)
#pragma unroll
            for (int i = 0; i < 4; i++) {
                int r = row0 + rf * 16 + q * 4 + i;
                if (r < NN) {
                    T[(size_t)r * N + col] = f2bf(acc1[rf][nt][i]);
                    U[(size_t)r * N + col] = acc2[rf][nt][i] + bv;
                }
            }
    }
}

extern "C" void kernel_launch(void* const* d_in, const int* in_sizes, int n_in,
                              void* d_out, int out_size, void* d_ws, size_t ws_size,
                              hipStream_t stream) {
    const void* x_raw  = d_in[0];
    const int*  ei     = (const int*)d_in[1];
    const void* W1l    = d_in[2];
    const void* b1     = d_in[3];
    const void* W1r    = d_in[4];
    const void* W2l    = d_in[5];
    const void* b2     = d_in[6];
    const void* W2r    = d_in[7];

    uint8_t* ws = (uint8_t*)d_ws;
    size_t off = 0;
    auto alloc = [&](size_t b) -> void* {
        void* p = ws + off;
        off += (b + 255) & ~(size_t)255;
        return p;
    };
    int*      flags       = (int*)alloc(256);
    int*      histM       = (int*)alloc((size_t)NB * NBLK * 4);
    int*      bucket_tot  = (int*)alloc((NB + 4) * 4);
    int*      bucket_base = (int*)alloc((NB + 4) * 4);
    int*      deg         = (int*)alloc((size_t)NN * 4);
    float*    inv_deg     = (float*)alloc((size_t)NN * 4);
    int*      row_start   = (int*)alloc((size_t)NN * 4);
    int*      csr         = (int*)alloc((size_t)NE * 4);
    uint32_t* xb          = (uint32_t*)alloc((size_t)NN * 64 * 4);
    uint16_t* bias_buf    = (uint16_t*)alloc(384 * 2);
    uint16_t* agg         = (uint16_t*)alloc((size_t)NN * 128 * 2);
    uint16_t* h           = (uint16_t*)alloc((size_t)NN * 256 * 2);
    uint16_t* t           = (uint16_t*)alloc((size_t)NN * 128 * 2);
    float*    u           = (float*)alloc((size_t)NN * 128 * 4);
    uint16_t* w1l_sw      = (uint16_t*)alloc(128 * 256 * 2);
    uint16_t* w1r_sw      = (uint16_t*)alloc(128 * 256 * 2);
    uint16_t* w2l_sw      = (uint16_t*)alloc(256 * 128 * 2);
    uint16_t* w2r_sw      = (uint16_t*)alloc(256 * 128 * 2);

    // staging aliases h (3.2 MB <= 25.6 MB; fully consumed by build_csr before h is written)
    uint32_t* staging = (uint32_t*)h;

    detect<<<1, 256, 0, stream>>>((const uint32_t*)x_raw, ei, flags);

    hist_pass<<<NBLK, 256, 0, stream>>>(ei, flags, histM);
    scan_rows<<<NB, 512, 0, stream>>>(histM, bucket_tot);
    scan_tot<<<1, 256, 0, stream>>>(bucket_tot, bucket_base);
    scatter_pass<<<NBLK, 256, 0, stream>>>(ei, flags, histM, bucket_base, staging);
    build_csr<<<NB, 256, 0, stream>>>(staging, bucket_base, row_start, deg, inv_deg, csr);

    norm_x<<<(NN * 64 + 255) / 256, 256, 0, stream>>>(x_raw, flags, xb);
    norm_weights_sw<<<66, 256, 0, stream>>>(W1l, b1, W1r, W2l, b2, W2r, flags,
                                            w1l_sw, w1r_sw, w2l_sw, w2r_sw, bias_buf);

    // layer 1: agg = A·x ; h = relu(agg@W1l + x@W1r + b1)
    agg_mean_128<<<NN / 4, 256, 0, stream>>>(xb, row_start, deg, csr, inv_deg, (uint32_t*)agg);
    gemm_dualA_breg<128, 256><<<(NN + 63) / 64, 256, 0, stream>>>(agg, (const uint16_t*)xb,
                                                                  w1l_sw, w1r_sw, bias_buf, h);
    // layer 2: t = h@W2l, u = h@W2r + b2 ; out = A·t + u
    gemm_dualB_breg<256, 128><<<(NN + 63) / 64, 256, 0, stream>>>(h, w2l_sw, w2r_sw, bias_buf + 256, t, u);
    agg_final_128<<<NN / 4, 256, 0, stream>>>((const uint32_t*)t, row_start, deg, csr, inv_deg,
                                              (const float2*)u, (float2*)d_out);
}